// Round 3
// baseline (382.555 us; speedup 1.0000x reference)
//
#include <hip/hip_runtime.h>
#include <math.h>

#define B_ 2
#define C_ 1024
#define D_ 1024
#define H_ 16
#define DH_ 64
#define EPSF 1e-8f

typedef __bf16 bf16;
typedef __attribute__((ext_vector_type(4))) __bf16 bf16x4;
typedef __attribute__((ext_vector_type(8))) __bf16 bf16x8;
typedef __attribute__((ext_vector_type(4))) float f32x4;

__device__ inline f32x4 mfma16(bf16x8 a, bf16x8 b, f32x4 c) {
  return __builtin_amdgcn_mfma_f32_16x16x32_bf16(a, b, c, 0, 0, 0);
}

// clamped exp: with correct data |x| < ~4 so the clamp never binds; exists so garbage
// stays finite & localizable. fmaxf/fminf also sanitize NaN per IEEE.
__device__ inline float expc(float x) { return __expf(fminf(fmaxf(x, -60.f), 60.f)); }

// ---------------- RMSNorm (fp32 in, bf16 out): one block per row, per-position w/b ----------------
__global__ __launch_bounds__(256) void rmsnorm_f32_kernel(const float* __restrict__ x,
                                                          const float* __restrict__ w,
                                                          const float* __restrict__ b,
                                                          bf16* __restrict__ out) {
  int row = blockIdx.x;
  int c = row & (C_ - 1);
  int t = threadIdx.x;
  float4 xv = *(const float4*)(x + (size_t)row * D_ + t * 4);
  float ss = xv.x * xv.x + xv.y * xv.y + xv.z * xv.z + xv.w * xv.w;
#pragma unroll
  for (int m = 1; m < 64; m <<= 1) ss += __shfl_xor(ss, m, 64);
  __shared__ float red[4];
  if ((t & 63) == 0) red[t >> 6] = ss;
  __syncthreads();
  float tot = red[0] + red[1] + red[2] + red[3];
  float inv = rsqrtf(tot * (1.0f / D_) + EPSF);
  float4 wv = *(const float4*)(w + (size_t)c * D_ + t * 4);
  float4 bv = *(const float4*)(b + (size_t)c * D_ + t * 4);
  bf16x4 ov;
  ov[0] = (bf16)(wv.x * (xv.x * inv) + bv.x);
  ov[1] = (bf16)(wv.y * (xv.y * inv) + bv.y);
  ov[2] = (bf16)(wv.z * (xv.z * inv) + bv.z);
  ov[3] = (bf16)(wv.w * (xv.w * inv) + bv.w);
  *(bf16x4*)(out + (size_t)row * D_ + t * 4) = ov;
}

// ---------------- RMSNorm (bf16 in, bf16 out) ----------------
__global__ __launch_bounds__(256) void rmsnorm_bf16_kernel(const bf16* __restrict__ x,
                                                           const float* __restrict__ w,
                                                           const float* __restrict__ b,
                                                           bf16* __restrict__ out) {
  int row = blockIdx.x;
  int c = row & (C_ - 1);
  int t = threadIdx.x;
  bf16x4 xv = *(const bf16x4*)(x + (size_t)row * D_ + t * 4);
  float f0 = (float)xv[0], f1 = (float)xv[1], f2 = (float)xv[2], f3 = (float)xv[3];
  float ss = f0 * f0 + f1 * f1 + f2 * f2 + f3 * f3;
#pragma unroll
  for (int m = 1; m < 64; m <<= 1) ss += __shfl_xor(ss, m, 64);
  __shared__ float red[4];
  if ((t & 63) == 0) red[t >> 6] = ss;
  __syncthreads();
  float tot = red[0] + red[1] + red[2] + red[3];
  float inv = rsqrtf(tot * (1.0f / D_) + EPSF);
  float4 wv = *(const float4*)(w + (size_t)c * D_ + t * 4);
  float4 bv = *(const float4*)(b + (size_t)c * D_ + t * 4);
  bf16x4 ov;
  ov[0] = (bf16)(wv.x * (f0 * inv) + bv.x);
  ov[1] = (bf16)(wv.y * (f1 * inv) + bv.y);
  ov[2] = (bf16)(wv.z * (f2 * inv) + bv.z);
  ov[3] = (bf16)(wv.w * (f3 * inv) + bv.w);
  *(bf16x4*)(out + (size_t)row * D_ + t * 4) = ov;
}

// ---------------- GEMM: C[m,n] = sum_k A[m,k] W[n,k] (+bias[n]) (+R[m,n]) ----------------
// A is bf16 (internal activation); W is fp32 (harness input), converted to bf16 in-register
// during staging. Register-staged LDS (m93-style) this round.
#define BM 128
#define BN 128
#define BK 32
__global__ __launch_bounds__(256) void gemm_bt_kernel(const bf16* __restrict__ A,
                                                      const float* __restrict__ W,
                                                      const float* __restrict__ bias,
                                                      const bf16* __restrict__ R,
                                                      bf16* __restrict__ Cout,
                                                      int M, int N, int K) {
  __shared__ bf16 sa[BM * BK];
  __shared__ bf16 sb[BN * BK];
  int t = threadIdx.x;
  int l = t & 63;
  int w = t >> 6;
  int m0 = blockIdx.y * BM;
  int n0 = blockIdx.x * BN;
  int wm = (w >> 1) * 64, wn = (w & 1) * 64;
  int lm = l & 15, lq = l >> 4;
  int r0 = t >> 2;       // 0..63
  int c8 = (t & 3) * 8;  // 0,8,16,24
  f32x4 acc[4][4] = {};

  for (int k0 = 0; k0 < K; k0 += BK) {
    int4 a0 = *(const int4*)(A + (size_t)(m0 + r0) * K + k0 + c8);
    int4 a1 = *(const int4*)(A + (size_t)(m0 + 64 + r0) * K + k0 + c8);
    const float* w0p = W + (size_t)(n0 + r0) * K + k0 + c8;
    const float* w1p = W + (size_t)(n0 + 64 + r0) * K + k0 + c8;
    float4 w00 = *(const float4*)(w0p);
    float4 w01 = *(const float4*)(w0p + 4);
    float4 w10 = *(const float4*)(w1p);
    float4 w11 = *(const float4*)(w1p + 4);
    bf16x8 wb0, wb1;
    wb0[0] = (bf16)w00.x; wb0[1] = (bf16)w00.y; wb0[2] = (bf16)w00.z; wb0[3] = (bf16)w00.w;
    wb0[4] = (bf16)w01.x; wb0[5] = (bf16)w01.y; wb0[6] = (bf16)w01.z; wb0[7] = (bf16)w01.w;
    wb1[0] = (bf16)w10.x; wb1[1] = (bf16)w10.y; wb1[2] = (bf16)w10.z; wb1[3] = (bf16)w10.w;
    wb1[4] = (bf16)w11.x; wb1[5] = (bf16)w11.y; wb1[6] = (bf16)w11.z; wb1[7] = (bf16)w11.w;
    __syncthreads();  // prior iter's LDS reads done before overwrite
    *(int4*)(sa + r0 * BK + c8) = a0;
    *(int4*)(sa + (64 + r0) * BK + c8) = a1;
    *(bf16x8*)(sb + r0 * BK + c8) = wb0;
    *(bf16x8*)(sb + (64 + r0) * BK + c8) = wb1;
    __syncthreads();
    bf16x8 af[4], bfr[4];
#pragma unroll
    for (int mt = 0; mt < 4; ++mt)
      af[mt] = *(const bf16x8*)(sa + (wm + mt * 16 + lm) * BK + lq * 8);
#pragma unroll
    for (int nt = 0; nt < 4; ++nt)
      bfr[nt] = *(const bf16x8*)(sb + (wn + nt * 16 + lm) * BK + lq * 8);
#pragma unroll
    for (int mt = 0; mt < 4; ++mt)
#pragma unroll
      for (int nt = 0; nt < 4; ++nt)
        acc[mt][nt] = mfma16(af[mt], bfr[nt], acc[mt][nt]);
  }
#pragma unroll
  for (int mt = 0; mt < 4; ++mt)
#pragma unroll
    for (int nt = 0; nt < 4; ++nt) {
      int col = n0 + wn + nt * 16 + lm;
      float bb = bias ? bias[col] : 0.0f;
#pragma unroll
      for (int r = 0; r < 4; ++r) {
        int row = m0 + wm + mt * 16 + lq * 4 + r;
        float v = acc[mt][nt][r] + bb;
        if (R) v += (float)R[(size_t)row * N + col];
        Cout[(size_t)row * N + col] = (bf16)v;
      }
    }
}

// ---------------- RoPE: rotated q,k in head-major [b][h][c][dh] ----------------
__global__ __launch_bounds__(256) void rope_kernel(const bf16* __restrict__ qkv,
                                                   bf16* __restrict__ qr,
                                                   bf16* __restrict__ kr) {
  int idx = blockIdx.x * 256 + threadIdx.x;  // B*H*C*(DH/2) = 1M
  int i = idx & 31;
  int c = (idx >> 5) & (C_ - 1);
  int h = (idx >> 15) & (H_ - 1);
  int b = idx >> 19;
  // theta = 10000^(-2*(i-1)/64)   (reference uses (i-1)!)
  float e2 = -13.28771237954945f * (2.0f * ((float)i - 1.0f) / 64.0f);
  float theta = exp2f(e2);
  float ang = (float)c * theta;
  float sv = __sinf(ang), cv = __cosf(ang);
  size_t base = (size_t)(b * C_ + c) * (3 * D_) + h * DH_ + 2 * i;
  float qe = (float)qkv[base], qo = (float)qkv[base + 1];
  float ke = (float)qkv[base + D_], ko = (float)qkv[base + D_ + 1];
  size_t ob = ((size_t)((b * H_ + h) * C_) + c) * DH_ + 2 * i;
  qr[ob] = (bf16)(qe * cv + qo * sv);
  qr[ob + 1] = (bf16)(qo * cv - qe * sv);
  kr[ob] = (bf16)(ke * cv + ko * sv);
  kr[ob + 1] = (bf16)(ko * cv - ke * sv);
}

// ---------------- V transpose: vt[b][h][dh][c] ----------------
__global__ __launch_bounds__(256) void transpose_v_kernel(const bf16* __restrict__ qkv,
                                                          bf16* __restrict__ vt) {
  __shared__ bf16 tile[64][65];
  int t = threadIdx.x;
  int blk = blockIdx.x;  // B*H*(C/64)
  int ct = blk & 15;
  int h = (blk >> 4) & 15;
  int b = blk >> 8;
  int c0 = ct * 64;
#pragma unroll
  for (int p = 0; p < 16; ++p) {
    int lin = p * 256 + t;
    int cl = lin >> 6, dh = lin & 63;
    tile[dh][cl] = qkv[(size_t)(b * C_ + c0 + cl) * (3 * D_) + 2 * D_ + h * DH_ + dh];
  }
  __syncthreads();
  size_t vbase = (size_t)((b * H_ + h) * DH_) * C_;
#pragma unroll
  for (int p = 0; p < 16; ++p) {
    int lin = p * 256 + t;
    int dh = lin >> 6, cl = lin & 63;
    vt[vbase + (size_t)dh * C_ + c0 + cl] = tile[dh][cl];
  }
}

// ---------------- Fused attention ----------------
// num = exp(qr.kr * s) masked j<=i ; den = sum_all_j exp(q.k * s) (unrotated, unmasked)
// y_i = (1/den_i) * sum_{j<=i} num_ij * v_j
__global__ __launch_bounds__(256) void attn_kernel(const bf16* __restrict__ qkv,
                                                   const bf16* __restrict__ qr,
                                                   const bf16* __restrict__ kr,
                                                   const bf16* __restrict__ vt,
                                                   bf16* __restrict__ y) {
  __shared__ bf16 p_lds[4][16][32];
  int t = threadIdx.x, l = t & 63, w = t >> 6;
  int blk = blockIdx.x;  // B*H*(C/64)
  int it = blk & 15;
  int h = (blk >> 4) & 15;
  int b = blk >> 8;
  int i_base = it * 64 + w * 16;
  int lm = l & 15, lq = l >> 4;
  const float scale = 0.125f;

  size_t hq = (size_t)h * DH_;
  size_t qrow = (size_t)(b * C_ + i_base + lm) * (3 * D_) + hq;
  size_t hb = (size_t)((b * H_ + h) * C_);
  bf16x8 qp[2], qrf[2];
#pragma unroll
  for (int kk = 0; kk < 2; ++kk) {
    qp[kk] = *(const bf16x8*)(qkv + qrow + kk * 32 + lq * 8);
    qrf[kk] = *(const bf16x8*)(qr + (hb + i_base + lm) * DH_ + kk * 32 + lq * 8);
  }

  float den[4] = {0.f, 0.f, 0.f, 0.f};
  f32x4 yacc[4] = {};
  int i_max = i_base + 15;
  size_t kbase = (size_t)(b * C_) * (3 * D_) + D_ + hq;
  size_t krbase = hb * DH_;
  size_t vtbase = (size_t)((b * H_ + h) * DH_) * C_;

  for (int j0 = 0; j0 < C_; j0 += 32) {
#pragma unroll
    for (int js = 0; js < 32; js += 16) {
      const bf16* kp = qkv + kbase + (size_t)(j0 + js + lm) * (3 * D_);
      bf16x8 kf0 = *(const bf16x8*)(kp + lq * 8);
      bf16x8 kf1 = *(const bf16x8*)(kp + 32 + lq * 8);
      f32x4 s = {0.f, 0.f, 0.f, 0.f};
      s = mfma16(qp[0], kf0, s);
      s = mfma16(qp[1], kf1, s);
#pragma unroll
      for (int r = 0; r < 4; ++r) den[r] += expc(s[r] * scale);
    }
    if (j0 <= i_max) {
#pragma unroll
      for (int js = 0; js < 32; js += 16) {
        const bf16* kp = kr + krbase + (size_t)(j0 + js + lm) * DH_;
        bf16x8 kf0 = *(const bf16x8*)(kp + lq * 8);
        bf16x8 kf1 = *(const bf16x8*)(kp + 32 + lq * 8);
        f32x4 s = {0.f, 0.f, 0.f, 0.f};
        s = mfma16(qrf[0], kf0, s);
        s = mfma16(qrf[1], kf1, s);
#pragma unroll
        for (int r = 0; r < 4; ++r) {
          int jg = j0 + js + lm;
          int ig = i_base + lq * 4 + r;
          float p = (jg <= ig) ? expc(s[r] * scale) : 0.0f;
          p_lds[w][lq * 4 + r][js + lm] = (bf16)p;
        }
      }
      __builtin_amdgcn_wave_barrier();
      bf16x8 pf = *(const bf16x8*)(&p_lds[w][lm][lq * 8]);
#pragma unroll
      for (int tt = 0; tt < 4; ++tt) {
        bf16x8 vf = *(const bf16x8*)(vt + vtbase + (size_t)(tt * 16 + lm) * C_ + j0 + lq * 8);
        yacc[tt] = mfma16(pf, vf, yacc[tt]);
      }
      __builtin_amdgcn_wave_barrier();
    }
  }
  float inv[4];
#pragma unroll
  for (int r = 0; r < 4; ++r) {
    float d = den[r];
    d += __shfl_xor(d, 1, 64);
    d += __shfl_xor(d, 2, 64);
    d += __shfl_xor(d, 4, 64);
    d += __shfl_xor(d, 8, 64);
    inv[r] = 1.0f / d;  // den >= 16*exp(-60) > 0 by construction
  }
#pragma unroll
  for (int tt = 0; tt < 4; ++tt)
#pragma unroll
    for (int r = 0; r < 4; ++r) {
      int ig = i_base + lq * 4 + r;
      y[(size_t)(b * C_ + ig) * D_ + hq + tt * 16 + lm] = (bf16)(yacc[tt][r] * inv[r]);
    }
}

// ---------------- FFN gate epilogue: out = x3 + (wx*sigmoid(beta*wx))*hv  (fp32 out) ----------------
__global__ __launch_bounds__(256) void ffn_final_kernel(const bf16* __restrict__ x3,
                                                        const bf16* __restrict__ wx,
                                                        const bf16* __restrict__ hv,
                                                        const float* __restrict__ beta_p,
                                                        float* __restrict__ out, int n) {
  int idx = blockIdx.x * 256 + threadIdx.x;
  if (idx >= n) return;
  float beta = beta_p[0];
  float z = (float)wx[idx];
  float sw = z / (1.0f + expc(-beta * z));
  out[idx] = (float)x3[idx] + sw * (float)hv[idx];
}

extern "C" void kernel_launch(void* const* d_in, const int* in_sizes, int n_in,
                              void* d_out, int out_size, void* d_ws, size_t ws_size,
                              hipStream_t stream) {
  // Reference dtypes are float32 for ALL inputs and the output.
  const float* x = (const float*)d_in[0];
  const float* rms_w = (const float*)d_in[1];
  const float* rms_b = (const float*)d_in[2];
  const float* Wqkv = (const float*)d_in[3];
  const float* Wout = (const float*)d_in[4];
  const float* bout = (const float*)d_in[5];
  const float* Wf = (const float*)d_in[6];
  const float* bfp = (const float*)d_in[7];
  const float* Ww = (const float*)d_in[8];
  const float* bw = (const float*)d_in[9];
  const float* Wv = (const float*)d_in[10];
  const float* bv = (const float*)d_in[11];
  const float* beta = (const float*)d_in[12];
  float* out = (float*)d_out;

  // Workspace layout (bf16 elems). Peak = 14M elems = 28 MB.
  bf16* ws = (bf16*)d_ws;
  const size_t MC = (size_t)B_ * C_;  // 2048
  const size_t M1 = MC * D_;          // 2M elems
  bf16* x1 = ws + 0 * M1;             // [0,2M)
  bf16* qkv = ws + 1 * M1;            // [2M,8M)
  bf16* qr = ws + 4 * M1;             // [8M,10M)
  bf16* kr = ws + 5 * M1;             // [10M,12M)
  bf16* vt = ws + 6 * M1;             // [12M,14M)
  bf16* y = (bf16*)d_out;             // d_out is 8 MB fp32; y needs 4 MB bf16, dead before final write
  // post-attention aliases (regions dead by then):
  bf16* x2 = qr;
  bf16* x3 = kr;
  bf16* hbuf = vt;
  bf16* wx = qkv;        // [2M,4M)
  bf16* hv = qkv + M1;   // [4M,6M)

  rmsnorm_f32_kernel<<<MC, 256, 0, stream>>>(x, rms_w, rms_b, x1);
  gemm_bt_kernel<<<dim3(3 * D_ / BN, MC / BM), 256, 0, stream>>>(x1, Wqkv, nullptr, nullptr, qkv,
                                                                 MC, 3 * D_, D_);
  rope_kernel<<<(B_ * H_ * C_ * (DH_ / 2)) / 256, 256, 0, stream>>>(qkv, qr, kr);
  transpose_v_kernel<<<B_ * H_ * (C_ / 64), 256, 0, stream>>>(qkv, vt);
  attn_kernel<<<B_ * H_ * (C_ / 64), 256, 0, stream>>>(qkv, qr, kr, vt, y);
  gemm_bt_kernel<<<dim3(D_ / BN, MC / BM), 256, 0, stream>>>(y, Wout, bout, x1, x2, MC, D_, D_);
  rmsnorm_bf16_kernel<<<MC, 256, 0, stream>>>(x2, rms_w, rms_b, x3);
  gemm_bt_kernel<<<dim3(D_ / BN, MC / BM), 256, 0, stream>>>(x3, Wf, bfp, nullptr, hbuf, MC, D_, D_);
  gemm_bt_kernel<<<dim3(D_ / BN, MC / BM), 256, 0, stream>>>(hbuf, Ww, bw, nullptr, wx, MC, D_, D_);
  gemm_bt_kernel<<<dim3(D_ / BN, MC / BM), 256, 0, stream>>>(hbuf, Wv, bv, nullptr, hv, MC, D_, D_);
  ffn_final_kernel<<<(int)((MC * D_) / 256), 256, 0, stream>>>(x3, wx, hv, beta, out, (int)(MC * D_));
}

// Round 4
// 295.076 us; speedup vs baseline: 1.2965x; 1.2965x over previous
//
#include <hip/hip_runtime.h>
#include <math.h>

#define B_ 2
#define C_ 1024
#define D_ 1024
#define H_ 16
#define DH_ 64
#define EPSF 1e-8f
#define BK 32

typedef __bf16 bf16;
typedef __attribute__((ext_vector_type(4))) __bf16 bf16x4;
typedef __attribute__((ext_vector_type(8))) __bf16 bf16x8;
typedef __attribute__((ext_vector_type(4))) float f32x4;

__device__ inline f32x4 mfma16(bf16x8 a, bf16x8 b, f32x4 c) {
  return __builtin_amdgcn_mfma_f32_16x16x32_bf16(a, b, c, 0, 0, 0);
}

// clamped exp: with correct data |x| < ~4 so the clamp never binds.
__device__ inline float expc(float x) { return __expf(fminf(fmaxf(x, -60.f), 60.f)); }

// ---------------- fp32 -> bf16 convert (weights), n multiple of 1024 ----------------
__global__ __launch_bounds__(256) void cvt_kernel(const float* __restrict__ src,
                                                  bf16* __restrict__ dst) {
  int idx = (blockIdx.x * 256 + threadIdx.x) * 4;
  float4 v = *(const float4*)(src + idx);
  bf16x4 o;
  o[0] = (bf16)v.x; o[1] = (bf16)v.y; o[2] = (bf16)v.z; o[3] = (bf16)v.w;
  *(bf16x4*)(dst + idx) = o;
}

// ---------------- RMSNorm (fp32 in, bf16 out) ----------------
__global__ __launch_bounds__(256) void rmsnorm_f32_kernel(const float* __restrict__ x,
                                                          const float* __restrict__ w,
                                                          const float* __restrict__ b,
                                                          bf16* __restrict__ out) {
  int row = blockIdx.x;
  int c = row & (C_ - 1);
  int t = threadIdx.x;
  float4 xv = *(const float4*)(x + (size_t)row * D_ + t * 4);
  float ss = xv.x * xv.x + xv.y * xv.y + xv.z * xv.z + xv.w * xv.w;
#pragma unroll
  for (int m = 1; m < 64; m <<= 1) ss += __shfl_xor(ss, m, 64);
  __shared__ float red[4];
  if ((t & 63) == 0) red[t >> 6] = ss;
  __syncthreads();
  float tot = red[0] + red[1] + red[2] + red[3];
  float inv = rsqrtf(tot * (1.0f / D_) + EPSF);
  float4 wv = *(const float4*)(w + (size_t)c * D_ + t * 4);
  float4 bv = *(const float4*)(b + (size_t)c * D_ + t * 4);
  bf16x4 ov;
  ov[0] = (bf16)(wv.x * (xv.x * inv) + bv.x);
  ov[1] = (bf16)(wv.y * (xv.y * inv) + bv.y);
  ov[2] = (bf16)(wv.z * (xv.z * inv) + bv.z);
  ov[3] = (bf16)(wv.w * (xv.w * inv) + bv.w);
  *(bf16x4*)(out + (size_t)row * D_ + t * 4) = ov;
}

// ---------------- RMSNorm (bf16 in, bf16 out) ----------------
__global__ __launch_bounds__(256) void rmsnorm_bf16_kernel(const bf16* __restrict__ x,
                                                           const float* __restrict__ w,
                                                           const float* __restrict__ b,
                                                           bf16* __restrict__ out) {
  int row = blockIdx.x;
  int c = row & (C_ - 1);
  int t = threadIdx.x;
  bf16x4 xv = *(const bf16x4*)(x + (size_t)row * D_ + t * 4);
  float f0 = (float)xv[0], f1 = (float)xv[1], f2 = (float)xv[2], f3 = (float)xv[3];
  float ss = f0 * f0 + f1 * f1 + f2 * f2 + f3 * f3;
#pragma unroll
  for (int m = 1; m < 64; m <<= 1) ss += __shfl_xor(ss, m, 64);
  __shared__ float red[4];
  if ((t & 63) == 0) red[t >> 6] = ss;
  __syncthreads();
  float tot = red[0] + red[1] + red[2] + red[3];
  float inv = rsqrtf(tot * (1.0f / D_) + EPSF);
  float4 wv = *(const float4*)(w + (size_t)c * D_ + t * 4);
  float4 bv = *(const float4*)(b + (size_t)c * D_ + t * 4);
  bf16x4 ov;
  ov[0] = (bf16)(wv.x * (f0 * inv) + bv.x);
  ov[1] = (bf16)(wv.y * (f1 * inv) + bv.y);
  ov[2] = (bf16)(wv.z * (f2 * inv) + bv.z);
  ov[3] = (bf16)(wv.w * (f3 * inv) + bv.w);
  *(bf16x4*)(out + (size_t)row * D_ + t * 4) = ov;
}

// ---------------- GEMM: C[m,n] = sum_k A[m,k] W[n,k] (+bias[n]) (+R[m,n]) ----------------
// All-bf16, register-staged LDS, templated tile. 4 waves, wave w covers rows [w*BMt/4, ...).
template <int BMt, int BNt>
__global__ __launch_bounds__(256) void gemm_bt_bf16(const bf16* __restrict__ A,
                                                    const bf16* __restrict__ W,
                                                    const float* __restrict__ bias,
                                                    const bf16* __restrict__ R,
                                                    bf16* __restrict__ Cout,
                                                    int M, int N, int K) {
  constexpr int MT = BMt / 64;  // m-tiles per wave (wave covers BMt/4 = MT*16 rows)
  constexpr int NT = BNt / 16;  // n-tiles per wave (all BNt)
  constexpr int PB = BNt / 64;  // B staging passes
  __shared__ bf16 sa[BMt * BK];
  __shared__ bf16 sb[BNt * BK];
  int t = threadIdx.x, l = t & 63, w = t >> 6;
  int m0 = blockIdx.y * BMt, n0 = blockIdx.x * BNt;
  int wm = w * (BMt / 4);
  int lm = l & 15, lq = l >> 4;
  int r0 = t >> 2, c8 = (t & 3) * 8;
  f32x4 acc[MT][NT] = {};

  for (int k0 = 0; k0 < K; k0 += BK) {
    int4 ra[MT], rb[PB];
#pragma unroll
    for (int p = 0; p < MT; ++p)
      ra[p] = *(const int4*)(A + (size_t)(m0 + p * 64 + r0) * K + k0 + c8);
#pragma unroll
    for (int p = 0; p < PB; ++p)
      rb[p] = *(const int4*)(W + (size_t)(n0 + p * 64 + r0) * K + k0 + c8);
    __syncthreads();  // prior iter's LDS reads done before overwrite
#pragma unroll
    for (int p = 0; p < MT; ++p) *(int4*)(sa + (p * 64 + r0) * BK + c8) = ra[p];
#pragma unroll
    for (int p = 0; p < PB; ++p) *(int4*)(sb + (p * 64 + r0) * BK + c8) = rb[p];
    __syncthreads();
    bf16x8 af[MT], bfr[NT];
#pragma unroll
    for (int mt = 0; mt < MT; ++mt)
      af[mt] = *(const bf16x8*)(sa + (wm + mt * 16 + lm) * BK + lq * 8);
#pragma unroll
    for (int nt = 0; nt < NT; ++nt)
      bfr[nt] = *(const bf16x8*)(sb + (nt * 16 + lm) * BK + lq * 8);
#pragma unroll
    for (int mt = 0; mt < MT; ++mt)
#pragma unroll
      for (int nt = 0; nt < NT; ++nt)
        acc[mt][nt] = mfma16(af[mt], bfr[nt], acc[mt][nt]);
  }
#pragma unroll
  for (int mt = 0; mt < MT; ++mt)
#pragma unroll
    for (int nt = 0; nt < NT; ++nt) {
      int col = n0 + nt * 16 + lm;
      float bb = bias ? bias[col] : 0.0f;
#pragma unroll
      for (int r = 0; r < 4; ++r) {
        int row = m0 + wm + mt * 16 + lq * 4 + r;
        float v = acc[mt][nt][r] + bb;
        if (R) v += (float)R[(size_t)row * N + col];
        Cout[(size_t)row * N + col] = (bf16)v;
      }
    }
}

// ---------------- RoPE: rotated q,k in head-major [b][h][c][dh] ----------------
__global__ __launch_bounds__(256) void rope_kernel(const bf16* __restrict__ qkv,
                                                   bf16* __restrict__ qr,
                                                   bf16* __restrict__ kr) {
  int idx = blockIdx.x * 256 + threadIdx.x;  // B*H*C*(DH/2) = 1M
  int i = idx & 31;
  int c = (idx >> 5) & (C_ - 1);
  int h = (idx >> 15) & (H_ - 1);
  int b = idx >> 19;
  // theta = 10000^(-2*(i-1)/64)   (reference uses (i-1)!)
  float e2 = -13.28771237954945f * (2.0f * ((float)i - 1.0f) / 64.0f);
  float theta = exp2f(e2);
  float ang = (float)c * theta;
  float sv = __sinf(ang), cv = __cosf(ang);
  size_t base = (size_t)(b * C_ + c) * (3 * D_) + h * DH_ + 2 * i;
  float qe = (float)qkv[base], qo = (float)qkv[base + 1];
  float ke = (float)qkv[base + D_], ko = (float)qkv[base + D_ + 1];
  size_t ob = ((size_t)((b * H_ + h) * C_) + c) * DH_ + 2 * i;
  qr[ob] = (bf16)(qe * cv + qo * sv);
  qr[ob + 1] = (bf16)(qo * cv - qe * sv);
  kr[ob] = (bf16)(ke * cv + ko * sv);
  kr[ob + 1] = (bf16)(ko * cv - ke * sv);
}

// ---------------- V transpose: vt[b][h][dh][c] ----------------
__global__ __launch_bounds__(256) void transpose_v_kernel(const bf16* __restrict__ qkv,
                                                          bf16* __restrict__ vt) {
  __shared__ bf16 tile[64][65];
  int t = threadIdx.x;
  int blk = blockIdx.x;  // B*H*(C/64)
  int ct = blk & 15;
  int h = (blk >> 4) & 15;
  int b = blk >> 8;
  int c0 = ct * 64;
#pragma unroll
  for (int p = 0; p < 16; ++p) {
    int lin = p * 256 + t;
    int cl = lin >> 6, dh = lin & 63;
    tile[dh][cl] = qkv[(size_t)(b * C_ + c0 + cl) * (3 * D_) + 2 * D_ + h * DH_ + dh];
  }
  __syncthreads();
  size_t vbase = (size_t)((b * H_ + h) * DH_) * C_;
#pragma unroll
  for (int p = 0; p < 16; ++p) {
    int lin = p * 256 + t;
    int dh = lin >> 6, cl = lin & 63;
    vt[vbase + (size_t)dh * C_ + c0 + cl] = tile[dh][cl];
  }
}

// ---------------- Fused attention, cooperative LDS staging ----------------
// num = exp(qr.kr*s) masked j<=i ; den = sum_all_j exp(q.k*s) (unrotated, unmasked)
// All 4 waves share K/Kr/V tiles staged in LDS (row pad +8 elems -> 2-way bank aliasing, free).
__global__ __launch_bounds__(256) void attn_kernel(const bf16* __restrict__ qkv,
                                                   const bf16* __restrict__ qr,
                                                   const bf16* __restrict__ kr,
                                                   const bf16* __restrict__ vt,
                                                   bf16* __restrict__ y) {
  __shared__ bf16 sk[64 * 72];   // unrotated K tile [j][dh]
  __shared__ bf16 skr[64 * 72];  // rotated K tile  [j][dh]
  __shared__ bf16 sv[64 * 72];   // V^T tile        [dh][j]
  __shared__ bf16 pl[4][16 * 72];  // per-wave P tile [i][j]
  int t = threadIdx.x, l = t & 63, w = t >> 6;
  int blk = blockIdx.x;  // B*H*(C/64)
  int it = blk & 15;
  int h = (blk >> 4) & 15;
  int b = blk >> 8;
  int i_base = it * 64 + w * 16;
  int lm = l & 15, lq = l >> 4;
  const float scale = 0.125f;

  size_t hq = (size_t)h * DH_;
  size_t qrow = (size_t)(b * C_ + i_base + lm) * (3 * D_) + hq;
  size_t hb = (size_t)((b * H_ + h) * C_);
  bf16x8 qp[2], qrf[2];
#pragma unroll
  for (int kk = 0; kk < 2; ++kk) {
    qp[kk] = *(const bf16x8*)(qkv + qrow + kk * 32 + lq * 8);
    qrf[kk] = *(const bf16x8*)(qr + (hb + i_base + lm) * DH_ + kk * 32 + lq * 8);
  }

  float den[4] = {0.f, 0.f, 0.f, 0.f};
  f32x4 yacc[4] = {};
  int i_max = i_base + 15;
  size_t kbase = (size_t)(b * C_) * (3 * D_) + D_ + hq;
  size_t krbase = hb * DH_;
  size_t vtbase = (size_t)((b * H_ + h) * DH_) * C_;
  int sr = t >> 3;       // 0..31 (row within staging pass)
  int sc = (t & 7) * 8;  // 0..56 (col, elems)

  for (int j0 = 0; j0 < C_; j0 += 64) {
    __syncthreads();  // prior iter's tile reads done
#pragma unroll
    for (int p = 0; p < 2; ++p) {
      int jr = p * 32 + sr;
      *(int4*)(sk + jr * 72 + sc) =
          *(const int4*)(qkv + kbase + (size_t)(j0 + jr) * (3 * D_) + sc);
      *(int4*)(skr + jr * 72 + sc) =
          *(const int4*)(kr + krbase + (size_t)(j0 + jr) * DH_ + sc);
      *(int4*)(sv + jr * 72 + sc) =
          *(const int4*)(vt + vtbase + (size_t)jr * C_ + j0 + sc);
    }
    __syncthreads();
    // denominator: all j, unrotated q.k
#pragma unroll
    for (int js = 0; js < 64; js += 16) {
      bf16x8 kf0 = *(const bf16x8*)(sk + (js + lm) * 72 + lq * 8);
      bf16x8 kf1 = *(const bf16x8*)(sk + (js + lm) * 72 + 32 + lq * 8);
      f32x4 s = {0.f, 0.f, 0.f, 0.f};
      s = mfma16(qp[0], kf0, s);
      s = mfma16(qp[1], kf1, s);
#pragma unroll
      for (int r = 0; r < 4; ++r) den[r] += expc(s[r] * scale);
    }
    // numerator + PV: only tiles intersecting the causal triangle (wave-uniform guard)
    if (j0 <= i_max) {
#pragma unroll
      for (int js = 0; js < 64; js += 16) {
        bf16x8 kf0 = *(const bf16x8*)(skr + (js + lm) * 72 + lq * 8);
        bf16x8 kf1 = *(const bf16x8*)(skr + (js + lm) * 72 + 32 + lq * 8);
        f32x4 s = {0.f, 0.f, 0.f, 0.f};
        s = mfma16(qrf[0], kf0, s);
        s = mfma16(qrf[1], kf1, s);
#pragma unroll
        for (int r = 0; r < 4; ++r) {
          int jg = j0 + js + lm;
          int ig = i_base + lq * 4 + r;
          float p = (jg <= ig) ? expc(s[r] * scale) : 0.0f;
          pl[w][(lq * 4 + r) * 72 + js + lm] = (bf16)p;
        }
      }
      __builtin_amdgcn_wave_barrier();
      bf16x8 pf0 = *(const bf16x8*)(pl[w] + lm * 72 + lq * 8);
      bf16x8 pf1 = *(const bf16x8*)(pl[w] + lm * 72 + 32 + lq * 8);
#pragma unroll
      for (int tt = 0; tt < 4; ++tt) {
        bf16x8 vf0 = *(const bf16x8*)(sv + (tt * 16 + lm) * 72 + lq * 8);
        bf16x8 vf1 = *(const bf16x8*)(sv + (tt * 16 + lm) * 72 + 32 + lq * 8);
        yacc[tt] = mfma16(pf0, vf0, mfma16(pf1, vf1, yacc[tt]));
      }
      __builtin_amdgcn_wave_barrier();
    }
  }
  float inv[4];
#pragma unroll
  for (int r = 0; r < 4; ++r) {
    float d = den[r];
    d += __shfl_xor(d, 1, 64);
    d += __shfl_xor(d, 2, 64);
    d += __shfl_xor(d, 4, 64);
    d += __shfl_xor(d, 8, 64);
    inv[r] = 1.0f / d;
  }
#pragma unroll
  for (int tt = 0; tt < 4; ++tt)
#pragma unroll
    for (int r = 0; r < 4; ++r) {
      int ig = i_base + lq * 4 + r;
      y[(size_t)(b * C_ + ig) * D_ + hq + tt * 16 + lm] = (bf16)(yacc[tt][r] * inv[r]);
    }
}

// ---------------- FFN gate epilogue: out = x3 + (wx*sigmoid(beta*wx))*hv (fp32 out) ----------------
__global__ __launch_bounds__(256) void ffn_final_kernel(const bf16* __restrict__ x3,
                                                        const bf16* __restrict__ wx,
                                                        const bf16* __restrict__ hv,
                                                        const float* __restrict__ beta_p,
                                                        float* __restrict__ out, int n) {
  int idx = blockIdx.x * 256 + threadIdx.x;
  if (idx >= n) return;
  float beta = beta_p[0];
  float z = (float)wx[idx];
  float sw = z / (1.0f + expc(-beta * z));
  out[idx] = (float)x3[idx] + sw * (float)hv[idx];
}

extern "C" void kernel_launch(void* const* d_in, const int* in_sizes, int n_in,
                              void* d_out, int out_size, void* d_ws, size_t ws_size,
                              hipStream_t stream) {
  const float* x = (const float*)d_in[0];
  const float* rms_w = (const float*)d_in[1];
  const float* rms_b = (const float*)d_in[2];
  const float* Wqkv = (const float*)d_in[3];
  const float* Wout = (const float*)d_in[4];
  const float* bout = (const float*)d_in[5];
  const float* Wf = (const float*)d_in[6];
  const float* bfp = (const float*)d_in[7];
  const float* Ww = (const float*)d_in[8];
  const float* bw = (const float*)d_in[9];
  const float* Wv = (const float*)d_in[10];
  const float* bv = (const float*)d_in[11];
  const float* beta = (const float*)d_in[12];
  float* out = (float*)d_out;

  // Workspace (bf16 elems), M1 = 2M. Peak live = 7*M1 = 28 MB (same as proven round 3).
  bf16* ws = (bf16*)d_ws;
  const size_t MC = (size_t)B_ * C_;  // 2048
  const size_t M1 = MC * D_;          // 2,097,152 elems
  bf16* x1 = ws + 0 * M1;             // [0,1)M1
  bf16* qkv = ws + 1 * M1;            // [1,4)M1
  bf16* qr = ws + 4 * M1;             // [4,5)M1
  bf16* kr = ws + 5 * M1;             // [5,6)M1
  bf16* vt = ws + 6 * M1;             // [6,7)M1
  bf16* y = (bf16*)d_out;             // 4 MB bf16 inside the 8 MB fp32 d_out; dead before final write
  // phase-scoped aliases (regions dead at time of use):
  bf16* Wqkv_bf = ws + 4 * M1;        // 1.5*M1, lives only during GEMM1 (qr/kr not yet written)
  bf16* Wslot = ws + 1 * M1;          // 0.5*M1, serial Wout/Wf/Ww/Wv conversions (qkv dead post-attn)
  bf16* x2 = ws + 4 * M1;
  bf16* x3 = ws + 5 * M1;
  bf16* hbuf = ws + 6 * M1;
  bf16* wx = ws + 2 * M1;
  bf16* hv = ws + 3 * M1;

  rmsnorm_f32_kernel<<<MC, 256, 0, stream>>>(x, rms_w, rms_b, x1);
  cvt_kernel<<<(3 * D_ * D_) / 1024, 256, 0, stream>>>(Wqkv, Wqkv_bf);
  gemm_bt_bf16<128, 64><<<dim3(3 * D_ / 64, MC / 128), 256, 0, stream>>>(
      x1, Wqkv_bf, nullptr, nullptr, qkv, MC, 3 * D_, D_);
  rope_kernel<<<(B_ * H_ * C_ * (DH_ / 2)) / 256, 256, 0, stream>>>(qkv, qr, kr);
  transpose_v_kernel<<<B_ * H_ * (C_ / 64), 256, 0, stream>>>(qkv, vt);
  attn_kernel<<<B_ * H_ * (C_ / 64), 256, 0, stream>>>(qkv, qr, kr, vt, y);
  cvt_kernel<<<(D_ * D_) / 1024, 256, 0, stream>>>(Wout, Wslot);
  gemm_bt_bf16<64, 64><<<dim3(D_ / 64, MC / 64), 256, 0, stream>>>(
      y, Wslot, bout, x1, x2, MC, D_, D_);
  rmsnorm_bf16_kernel<<<MC, 256, 0, stream>>>(x2, rms_w, rms_b, x3);
  cvt_kernel<<<(D_ * D_) / 1024, 256, 0, stream>>>(Wf, Wslot);
  gemm_bt_bf16<64, 64><<<dim3(D_ / 64, MC / 64), 256, 0, stream>>>(
      x3, Wslot, bfp, nullptr, hbuf, MC, D_, D_);
  cvt_kernel<<<(D_ * D_) / 1024, 256, 0, stream>>>(Ww, Wslot);
  gemm_bt_bf16<64, 64><<<dim3(D_ / 64, MC / 64), 256, 0, stream>>>(
      hbuf, Wslot, bw, nullptr, wx, MC, D_, D_);
  cvt_kernel<<<(D_ * D_) / 1024, 256, 0, stream>>>(Wv, Wslot);
  gemm_bt_bf16<64, 64><<<dim3(D_ / 64, MC / 64), 256, 0, stream>>>(
      hbuf, Wslot, bv, nullptr, hv, MC, D_, D_);
  ffn_final_kernel<<<(int)((MC * D_) / 256), 256, 0, stream>>>(x3, wx, hv, beta, out,
                                                               (int)(MC * D_));
}

// Round 5
// 270.854 us; speedup vs baseline: 1.4124x; 1.0894x over previous
//
#include <hip/hip_runtime.h>
#include <math.h>

#define B_ 2
#define C_ 1024
#define D_ 1024
#define H_ 16
#define DH_ 64
#define EPSF 1e-8f
#define BK 32

typedef __bf16 bf16;
typedef __attribute__((ext_vector_type(4))) __bf16 bf16x4;
typedef __attribute__((ext_vector_type(8))) __bf16 bf16x8;
typedef __attribute__((ext_vector_type(4))) float f32x4;

__device__ inline f32x4 mfma16(bf16x8 a, bf16x8 b, f32x4 c) {
  return __builtin_amdgcn_mfma_f32_16x16x32_bf16(a, b, c, 0, 0, 0);
}

// async global->LDS, 16B per lane. LDS dest contract: wave-uniform base + lane*16.
// Lane l of wave w passes lds = base + (w*64+l)*16B, so the uniform base is correct.
__device__ inline void async16(const bf16* g, bf16* l) {
  __builtin_amdgcn_global_load_lds((const __attribute__((address_space(1))) void*)g,
                                   (__attribute__((address_space(3))) void*)l, 16, 0, 0);
}

// clamped exp: with correct data |x| < ~4 so the clamp never binds.
__device__ inline float expc(float x) { return __expf(fminf(fmaxf(x, -60.f), 60.f)); }

// ---------------- fp32 -> bf16 convert (weights), n multiple of 1024 ----------------
__global__ __launch_bounds__(256) void cvt_kernel(const float* __restrict__ src,
                                                  bf16* __restrict__ dst) {
  int idx = (blockIdx.x * 256 + threadIdx.x) * 4;
  float4 v = *(const float4*)(src + idx);
  bf16x4 o;
  o[0] = (bf16)v.x; o[1] = (bf16)v.y; o[2] = (bf16)v.z; o[3] = (bf16)v.w;
  *(bf16x4*)(dst + idx) = o;
}

// ---------------- RMSNorm (fp32 in, bf16 out) ----------------
__global__ __launch_bounds__(256) void rmsnorm_f32_kernel(const float* __restrict__ x,
                                                          const float* __restrict__ w,
                                                          const float* __restrict__ b,
                                                          bf16* __restrict__ out) {
  int row = blockIdx.x;
  int c = row & (C_ - 1);
  int t = threadIdx.x;
  float4 xv = *(const float4*)(x + (size_t)row * D_ + t * 4);
  float ss = xv.x * xv.x + xv.y * xv.y + xv.z * xv.z + xv.w * xv.w;
#pragma unroll
  for (int m = 1; m < 64; m <<= 1) ss += __shfl_xor(ss, m, 64);
  __shared__ float red[4];
  if ((t & 63) == 0) red[t >> 6] = ss;
  __syncthreads();
  float tot = red[0] + red[1] + red[2] + red[3];
  float inv = rsqrtf(tot * (1.0f / D_) + EPSF);
  float4 wv = *(const float4*)(w + (size_t)c * D_ + t * 4);
  float4 bv = *(const float4*)(b + (size_t)c * D_ + t * 4);
  bf16x4 ov;
  ov[0] = (bf16)(wv.x * (xv.x * inv) + bv.x);
  ov[1] = (bf16)(wv.y * (xv.y * inv) + bv.y);
  ov[2] = (bf16)(wv.z * (xv.z * inv) + bv.z);
  ov[3] = (bf16)(wv.w * (xv.w * inv) + bv.w);
  *(bf16x4*)(out + (size_t)row * D_ + t * 4) = ov;
}

// ---------------- RMSNorm (bf16 in, bf16 out) ----------------
__global__ __launch_bounds__(256) void rmsnorm_bf16_kernel(const bf16* __restrict__ x,
                                                           const float* __restrict__ w,
                                                           const float* __restrict__ b,
                                                           bf16* __restrict__ out) {
  int row = blockIdx.x;
  int c = row & (C_ - 1);
  int t = threadIdx.x;
  bf16x4 xv = *(const bf16x4*)(x + (size_t)row * D_ + t * 4);
  float f0 = (float)xv[0], f1 = (float)xv[1], f2 = (float)xv[2], f3 = (float)xv[3];
  float ss = f0 * f0 + f1 * f1 + f2 * f2 + f3 * f3;
#pragma unroll
  for (int m = 1; m < 64; m <<= 1) ss += __shfl_xor(ss, m, 64);
  __shared__ float red[4];
  if ((t & 63) == 0) red[t >> 6] = ss;
  __syncthreads();
  float tot = red[0] + red[1] + red[2] + red[3];
  float inv = rsqrtf(tot * (1.0f / D_) + EPSF);
  float4 wv = *(const float4*)(w + (size_t)c * D_ + t * 4);
  float4 bv = *(const float4*)(b + (size_t)c * D_ + t * 4);
  bf16x4 ov;
  ov[0] = (bf16)(wv.x * (f0 * inv) + bv.x);
  ov[1] = (bf16)(wv.y * (f1 * inv) + bv.y);
  ov[2] = (bf16)(wv.z * (f2 * inv) + bv.z);
  ov[3] = (bf16)(wv.w * (f3 * inv) + bv.w);
  *(bf16x4*)(out + (size_t)row * D_ + t * 4) = ov;
}

// ---------------- GEMM (m97 structure): C[m,n] = sum_k A[m,k] W[n,k] (+bias) (+R) ----------------
// global_load_lds width-16 staging, 2x2 wave arrangement, BK=32.
// DUAL: grid-x spans 2*N1; blocks with n0g >= N1 use W2/b2/O2 (both outputs are M x N1).
template <int BMt, int BNt, bool DUAL>
__global__ __launch_bounds__(256) void gemm_lds(const bf16* __restrict__ A,
                                                const bf16* __restrict__ W1,
                                                const bf16* __restrict__ W2,
                                                const float* __restrict__ b1,
                                                const float* __restrict__ b2,
                                                const bf16* __restrict__ R,
                                                bf16* __restrict__ O1,
                                                bf16* __restrict__ O2,
                                                int M, int N1, int K) {
  constexpr int MT = BMt / 32;  // per-wave m tiles (wave covers BMt/2 rows)
  constexpr int NT = BNt / 32;  // per-wave n tiles (wave covers BNt/2 cols)
  __shared__ bf16 sa[BMt * BK];
  __shared__ bf16 sb[BNt * BK];
  int t = threadIdx.x, l = t & 63, w = t >> 6;
  int m0 = blockIdx.y * BMt;
  int n0g = blockIdx.x * BNt;
  const bf16* W = (!DUAL || n0g < N1) ? W1 : W2;
  const float* bias = (!DUAL || n0g < N1) ? b1 : b2;
  bf16* Cout = (!DUAL || n0g < N1) ? O1 : O2;
  int n0 = DUAL ? (n0g & (N1 - 1)) : n0g;
  int wm = (w >> 1) * (BMt / 2), wn = (w & 1) * (BNt / 2);
  int lm = l & 15, lq = l >> 4;
  f32x4 acc[MT][NT] = {};

  for (int k0 = 0; k0 < K; k0 += BK) {
    __syncthreads();  // prior iter's LDS reads complete before overwrite
#pragma unroll
    for (int p = 0; p < BMt / 64; ++p) {
      int lin = p * 256 + t;
      async16(A + (size_t)(m0 + (lin >> 2)) * K + k0 + (lin & 3) * 8, sa + lin * 8);
    }
#pragma unroll
    for (int p = 0; p < BNt / 64; ++p) {
      int lin = p * 256 + t;
      async16(W + (size_t)(n0 + (lin >> 2)) * K + k0 + (lin & 3) * 8, sb + lin * 8);
    }
    __syncthreads();  // includes vmcnt(0) drain of the lds-loads
    bf16x8 af[MT], bfr[NT];
#pragma unroll
    for (int mt = 0; mt < MT; ++mt)
      af[mt] = *(const bf16x8*)(sa + (wm + mt * 16 + lm) * BK + lq * 8);
#pragma unroll
    for (int nt = 0; nt < NT; ++nt)
      bfr[nt] = *(const bf16x8*)(sb + (wn + nt * 16 + lm) * BK + lq * 8);
#pragma unroll
    for (int mt = 0; mt < MT; ++mt)
#pragma unroll
      for (int nt = 0; nt < NT; ++nt)
        acc[mt][nt] = mfma16(af[mt], bfr[nt], acc[mt][nt]);
  }
#pragma unroll
  for (int mt = 0; mt < MT; ++mt)
#pragma unroll
    for (int nt = 0; nt < NT; ++nt) {
      int col = n0 + wn + nt * 16 + lm;
      float bb = bias ? bias[col] : 0.0f;
#pragma unroll
      for (int r = 0; r < 4; ++r) {
        int row = m0 + wm + mt * 16 + lq * 4 + r;
        float v = acc[mt][nt][r] + bb;
        if (R) v += (float)R[(size_t)row * N1 + col];
        Cout[(size_t)row * N1 + col] = (bf16)v;
      }
    }
}

// ---------------- RoPE: rotated q,k in head-major [b][h][c][dh] ----------------
__global__ __launch_bounds__(256) void rope_kernel(const bf16* __restrict__ qkv,
                                                   bf16* __restrict__ qr,
                                                   bf16* __restrict__ kr) {
  int idx = blockIdx.x * 256 + threadIdx.x;  // B*H*C*(DH/2) = 1M
  int i = idx & 31;
  int c = (idx >> 5) & (C_ - 1);
  int h = (idx >> 15) & (H_ - 1);
  int b = idx >> 19;
  // theta = 10000^(-2*(i-1)/64)   (reference uses (i-1)!)
  float e2 = -13.28771237954945f * (2.0f * ((float)i - 1.0f) / 64.0f);
  float theta = exp2f(e2);
  float ang = (float)c * theta;
  float sv = __sinf(ang), cv = __cosf(ang);
  size_t base = (size_t)(b * C_ + c) * (3 * D_) + h * DH_ + 2 * i;
  float qe = (float)qkv[base], qo = (float)qkv[base + 1];
  float ke = (float)qkv[base + D_], ko = (float)qkv[base + D_ + 1];
  size_t ob = ((size_t)((b * H_ + h) * C_) + c) * DH_ + 2 * i;
  qr[ob] = (bf16)(qe * cv + qo * sv);
  qr[ob + 1] = (bf16)(qo * cv - qe * sv);
  kr[ob] = (bf16)(ke * cv + ko * sv);
  kr[ob + 1] = (bf16)(ko * cv - ke * sv);
}

// ---------------- V transpose: vt[b][h][dh][c] ----------------
__global__ __launch_bounds__(256) void transpose_v_kernel(const bf16* __restrict__ qkv,
                                                          bf16* __restrict__ vt) {
  __shared__ bf16 tile[64][65];
  int t = threadIdx.x;
  int blk = blockIdx.x;  // B*H*(C/64)
  int ct = blk & 15;
  int h = (blk >> 4) & 15;
  int b = blk >> 8;
  int c0 = ct * 64;
#pragma unroll
  for (int p = 0; p < 16; ++p) {
    int lin = p * 256 + t;
    int cl = lin >> 6, dh = lin & 63;
    tile[dh][cl] = qkv[(size_t)(b * C_ + c0 + cl) * (3 * D_) + 2 * D_ + h * DH_ + dh];
  }
  __syncthreads();
  size_t vbase = (size_t)((b * H_ + h) * DH_) * C_;
#pragma unroll
  for (int p = 0; p < 16; ++p) {
    int lin = p * 256 + t;
    int dh = lin >> 6, cl = lin & 63;
    vt[vbase + (size_t)dh * C_ + c0 + cl] = tile[dh][cl];
  }
}

// ---------------- Fused attention, cooperative LDS staging ----------------
__global__ __launch_bounds__(256) void attn_kernel(const bf16* __restrict__ qkv,
                                                   const bf16* __restrict__ qr,
                                                   const bf16* __restrict__ kr,
                                                   const bf16* __restrict__ vt,
                                                   bf16* __restrict__ y) {
  __shared__ bf16 sk[64 * 72];   // unrotated K tile [j][dh]
  __shared__ bf16 skr[64 * 72];  // rotated K tile  [j][dh]
  __shared__ bf16 sv[64 * 72];   // V^T tile        [dh][j]
  __shared__ bf16 pl[4][16 * 72];  // per-wave P tile [i][j]
  int t = threadIdx.x, l = t & 63, w = t >> 6;
  int blk = blockIdx.x;  // B*H*(C/64)
  int it = blk & 15;
  int h = (blk >> 4) & 15;
  int b = blk >> 8;
  int i_base = it * 64 + w * 16;
  int lm = l & 15, lq = l >> 4;
  const float scale = 0.125f;

  size_t hq = (size_t)h * DH_;
  size_t qrow = (size_t)(b * C_ + i_base + lm) * (3 * D_) + hq;
  size_t hb = (size_t)((b * H_ + h) * C_);
  bf16x8 qp[2], qrf[2];
#pragma unroll
  for (int kk = 0; kk < 2; ++kk) {
    qp[kk] = *(const bf16x8*)(qkv + qrow + kk * 32 + lq * 8);
    qrf[kk] = *(const bf16x8*)(qr + (hb + i_base + lm) * DH_ + kk * 32 + lq * 8);
  }

  float den[4] = {0.f, 0.f, 0.f, 0.f};
  f32x4 yacc[4] = {};
  int i_max = i_base + 15;
  size_t kbase = (size_t)(b * C_) * (3 * D_) + D_ + hq;
  size_t krbase = hb * DH_;
  size_t vtbase = (size_t)((b * H_ + h) * DH_) * C_;
  int sr = t >> 3;       // 0..31 (row within staging pass)
  int sc = (t & 7) * 8;  // 0..56 (col, elems)

  for (int j0 = 0; j0 < C_; j0 += 64) {
    __syncthreads();  // prior iter's tile reads done
#pragma unroll
    for (int p = 0; p < 2; ++p) {
      int jr = p * 32 + sr;
      *(int4*)(sk + jr * 72 + sc) =
          *(const int4*)(qkv + kbase + (size_t)(j0 + jr) * (3 * D_) + sc);
      *(int4*)(skr + jr * 72 + sc) =
          *(const int4*)(kr + krbase + (size_t)(j0 + jr) * DH_ + sc);
      *(int4*)(sv + jr * 72 + sc) =
          *(const int4*)(vt + vtbase + (size_t)jr * C_ + j0 + sc);
    }
    __syncthreads();
    // denominator: all j, unrotated q.k
#pragma unroll
    for (int js = 0; js < 64; js += 16) {
      bf16x8 kf0 = *(const bf16x8*)(sk + (js + lm) * 72 + lq * 8);
      bf16x8 kf1 = *(const bf16x8*)(sk + (js + lm) * 72 + 32 + lq * 8);
      f32x4 s = {0.f, 0.f, 0.f, 0.f};
      s = mfma16(qp[0], kf0, s);
      s = mfma16(qp[1], kf1, s);
#pragma unroll
      for (int r = 0; r < 4; ++r) den[r] += expc(s[r] * scale);
    }
    // numerator + PV: only tiles intersecting the causal triangle (wave-uniform guard)
    if (j0 <= i_max) {
#pragma unroll
      for (int js = 0; js < 64; js += 16) {
        bf16x8 kf0 = *(const bf16x8*)(skr + (js + lm) * 72 + lq * 8);
        bf16x8 kf1 = *(const bf16x8*)(skr + (js + lm) * 72 + 32 + lq * 8);
        f32x4 s = {0.f, 0.f, 0.f, 0.f};
        s = mfma16(qrf[0], kf0, s);
        s = mfma16(qrf[1], kf1, s);
#pragma unroll
        for (int r = 0; r < 4; ++r) {
          int jg = j0 + js + lm;
          int ig = i_base + lq * 4 + r;
          float p = (jg <= ig) ? expc(s[r] * scale) : 0.0f;
          pl[w][(lq * 4 + r) * 72 + js + lm] = (bf16)p;
        }
      }
      __builtin_amdgcn_wave_barrier();
      bf16x8 pf0 = *(const bf16x8*)(pl[w] + lm * 72 + lq * 8);
      bf16x8 pf1 = *(const bf16x8*)(pl[w] + lm * 72 + 32 + lq * 8);
#pragma unroll
      for (int tt = 0; tt < 4; ++tt) {
        bf16x8 vf0 = *(const bf16x8*)(sv + (tt * 16 + lm) * 72 + lq * 8);
        bf16x8 vf1 = *(const bf16x8*)(sv + (tt * 16 + lm) * 72 + 32 + lq * 8);
        yacc[tt] = mfma16(pf0, vf0, mfma16(pf1, vf1, yacc[tt]));
      }
      __builtin_amdgcn_wave_barrier();
    }
  }
  float inv[4];
#pragma unroll
  for (int r = 0; r < 4; ++r) {
    float d = den[r];
    d += __shfl_xor(d, 1, 64);
    d += __shfl_xor(d, 2, 64);
    d += __shfl_xor(d, 4, 64);
    d += __shfl_xor(d, 8, 64);
    inv[r] = 1.0f / d;
  }
#pragma unroll
  for (int tt = 0; tt < 4; ++tt)
#pragma unroll
    for (int r = 0; r < 4; ++r) {
      int ig = i_base + lq * 4 + r;
      y[(size_t)(b * C_ + ig) * D_ + hq + tt * 16 + lm] = (bf16)(yacc[tt][r] * inv[r]);
    }
}

// ---------------- FFN gate epilogue: out = x3 + (wx*sigmoid(beta*wx))*hv (fp32 out) ----------------
__global__ __launch_bounds__(256) void ffn_final_kernel(const bf16* __restrict__ x3,
                                                        const bf16* __restrict__ wx,
                                                        const bf16* __restrict__ hv,
                                                        const float* __restrict__ beta_p,
                                                        float* __restrict__ out, int n) {
  int idx = blockIdx.x * 256 + threadIdx.x;
  if (idx >= n) return;
  float beta = beta_p[0];
  float z = (float)wx[idx];
  float sw = z / (1.0f + expc(-beta * z));
  out[idx] = (float)x3[idx] + sw * (float)hv[idx];
}

extern "C" void kernel_launch(void* const* d_in, const int* in_sizes, int n_in,
                              void* d_out, int out_size, void* d_ws, size_t ws_size,
                              hipStream_t stream) {
  const float* x = (const float*)d_in[0];
  const float* rms_w = (const float*)d_in[1];
  const float* rms_b = (const float*)d_in[2];
  const float* Wqkv = (const float*)d_in[3];
  const float* Wout = (const float*)d_in[4];
  const float* bout = (const float*)d_in[5];
  const float* Wf = (const float*)d_in[6];
  const float* bfp = (const float*)d_in[7];
  const float* Ww = (const float*)d_in[8];
  const float* bw = (const float*)d_in[9];
  const float* Wv = (const float*)d_in[10];
  const float* bv = (const float*)d_in[11];
  const float* beta = (const float*)d_in[12];
  float* out = (float*)d_out;

  // Workspace (bf16 elems), M1 = 2M elems. Peak live = 7*M1 = 28 MB (proven size).
  bf16* ws = (bf16*)d_ws;
  const size_t MC = (size_t)B_ * C_;  // 2048
  const size_t M1 = MC * D_;          // 2,097,152 elems
  bf16* x1 = ws + 0 * M1;             // [0,1)M1
  bf16* qkv = ws + 1 * M1;            // [1,4)M1
  bf16* qr = ws + 4 * M1;             // [4,5)M1
  bf16* kr = ws + 5 * M1;             // [5,6)M1
  bf16* vt = ws + 6 * M1;             // [6,7)M1
  bf16* y = (bf16*)d_out;             // 4 MB bf16 inside 8 MB fp32 d_out; dead before final write
  // phase-scoped aliases (regions dead at time of use):
  bf16* Wqkv_bf = ws + 4 * M1;        // 1.5*M1, lives only during GEMM1 (qr/kr not yet written)
  bf16* Wslot = ws + 1 * M1;          // 0.5*M1 (qkv dead post-attn)
  bf16* Wslot2 = ws + 1 * M1 + M1 / 2;  // 0.5*M1
  bf16* x2 = ws + 4 * M1;
  bf16* x3 = ws + 5 * M1;
  bf16* hbuf = ws + 6 * M1;
  bf16* wx = ws + 2 * M1;
  bf16* hv = ws + 3 * M1;

  rmsnorm_f32_kernel<<<MC, 256, 0, stream>>>(x, rms_w, rms_b, x1);
  cvt_kernel<<<(3 * D_ * D_) / 1024, 256, 0, stream>>>(Wqkv, Wqkv_bf);
  gemm_lds<128, 128, false><<<dim3(3 * D_ / 128, MC / 128), 256, 0, stream>>>(
      x1, Wqkv_bf, nullptr, nullptr, nullptr, nullptr, qkv, nullptr, MC, 3 * D_, D_);
  rope_kernel<<<(B_ * H_ * C_ * (DH_ / 2)) / 256, 256, 0, stream>>>(qkv, qr, kr);
  transpose_v_kernel<<<B_ * H_ * (C_ / 64), 256, 0, stream>>>(qkv, vt);
  attn_kernel<<<B_ * H_ * (C_ / 64), 256, 0, stream>>>(qkv, qr, kr, vt, y);
  cvt_kernel<<<(D_ * D_) / 1024, 256, 0, stream>>>(Wout, Wslot);
  gemm_lds<64, 128, false><<<dim3(D_ / 128, MC / 64), 256, 0, stream>>>(
      y, Wslot, nullptr, bout, nullptr, x1, x2, nullptr, MC, D_, D_);
  rmsnorm_bf16_kernel<<<MC, 256, 0, stream>>>(x2, rms_w, rms_b, x3);
  cvt_kernel<<<(D_ * D_) / 1024, 256, 0, stream>>>(Wf, Wslot);
  gemm_lds<64, 128, false><<<dim3(D_ / 128, MC / 64), 256, 0, stream>>>(
      x3, Wslot, nullptr, bfp, nullptr, nullptr, hbuf, nullptr, MC, D_, D_);
  cvt_kernel<<<(D_ * D_) / 1024, 256, 0, stream>>>(Ww, Wslot);
  cvt_kernel<<<(D_ * D_) / 1024, 256, 0, stream>>>(Wv, Wslot2);
  gemm_lds<128, 128, true><<<dim3(2 * D_ / 128, MC / 128), 256, 0, stream>>>(
      hbuf, Wslot, Wslot2, bw, bv, nullptr, wx, hv, MC, D_, D_);
  ffn_final_kernel<<<(int)((MC * D_) / 256), 256, 0, stream>>>(x3, wx, hv, beta, out,
                                                               (int)(MC * D_));
}

// Round 6
// 269.199 us; speedup vs baseline: 1.4211x; 1.0061x over previous
//
#include <hip/hip_runtime.h>
#include <math.h>

#define B_ 2
#define C_ 1024
#define D_ 1024
#define H_ 16
#define DH_ 64
#define EPSF 1e-8f
#define BK 32

typedef __bf16 bf16;
typedef __attribute__((ext_vector_type(4))) __bf16 bf16x4;
typedef __attribute__((ext_vector_type(8))) __bf16 bf16x8;
typedef __attribute__((ext_vector_type(4))) float f32x4;

__device__ inline f32x4 mfma16(bf16x8 a, bf16x8 b, f32x4 c) {
  return __builtin_amdgcn_mfma_f32_16x16x32_bf16(a, b, c, 0, 0, 0);
}

// async global->LDS, 16B per lane. LDS dest contract: wave-uniform base + lane*16.
__device__ inline void async16(const bf16* g, bf16* l) {
  __builtin_amdgcn_global_load_lds((const __attribute__((address_space(1))) void*)g,
                                   (__attribute__((address_space(3))) void*)l, 16, 0, 0);
}

// ---------------- fp32 -> bf16 convert, single weight (QKV) ----------------
__global__ __launch_bounds__(256) void cvt_kernel(const float* __restrict__ src,
                                                  bf16* __restrict__ dst) {
  int idx = (blockIdx.x * 256 + threadIdx.x) * 4;
  float4 v = *(const float4*)(src + idx);
  bf16x4 o;
  o[0] = (bf16)v.x; o[1] = (bf16)v.y; o[2] = (bf16)v.z; o[3] = (bf16)v.w;
  *(bf16x4*)(dst + idx) = o;
}

// ---------------- fp32 -> bf16 convert, 4 weights (Wout,Wf,Ww,Wv) to contiguous slots ----------------
__global__ __launch_bounds__(256) void cvt4_kernel(const float* __restrict__ s0,
                                                   const float* __restrict__ s1,
                                                   const float* __restrict__ s2,
                                                   const float* __restrict__ s3,
                                                   bf16* __restrict__ dst) {
  int which = blockIdx.x >> 10;               // D*D/1024 = 1024 blocks per weight
  int local = (blockIdx.x & 1023) * 1024 + threadIdx.x * 4;
  const float* src = which == 0 ? s0 : which == 1 ? s1 : which == 2 ? s2 : s3;
  float4 v = *(const float4*)(src + local);
  bf16x4 o;
  o[0] = (bf16)v.x; o[1] = (bf16)v.y; o[2] = (bf16)v.z; o[3] = (bf16)v.w;
  *(bf16x4*)(dst + (size_t)which * (D_ * D_) + local) = o;
}

// ---------------- RMSNorm (fp32 in, bf16 out) ----------------
__global__ __launch_bounds__(256) void rmsnorm_f32_kernel(const float* __restrict__ x,
                                                          const float* __restrict__ w,
                                                          const float* __restrict__ b,
                                                          bf16* __restrict__ out) {
  int row = blockIdx.x;
  int c = row & (C_ - 1);
  int t = threadIdx.x;
  float4 xv = *(const float4*)(x + (size_t)row * D_ + t * 4);
  float ss = xv.x * xv.x + xv.y * xv.y + xv.z * xv.z + xv.w * xv.w;
#pragma unroll
  for (int m = 1; m < 64; m <<= 1) ss += __shfl_xor(ss, m, 64);
  __shared__ float red[4];
  if ((t & 63) == 0) red[t >> 6] = ss;
  __syncthreads();
  float tot = red[0] + red[1] + red[2] + red[3];
  float inv = rsqrtf(tot * (1.0f / D_) + EPSF);
  float4 wv = *(const float4*)(w + (size_t)c * D_ + t * 4);
  float4 bv = *(const float4*)(b + (size_t)c * D_ + t * 4);
  bf16x4 ov;
  ov[0] = (bf16)(wv.x * (xv.x * inv) + bv.x);
  ov[1] = (bf16)(wv.y * (xv.y * inv) + bv.y);
  ov[2] = (bf16)(wv.z * (xv.z * inv) + bv.z);
  ov[3] = (bf16)(wv.w * (xv.w * inv) + bv.w);
  *(bf16x4*)(out + (size_t)row * D_ + t * 4) = ov;
}

// ---------------- RMSNorm (bf16 in, bf16 out) ----------------
__global__ __launch_bounds__(256) void rmsnorm_bf16_kernel(const bf16* __restrict__ x,
                                                           const float* __restrict__ w,
                                                           const float* __restrict__ b,
                                                           bf16* __restrict__ out) {
  int row = blockIdx.x;
  int c = row & (C_ - 1);
  int t = threadIdx.x;
  bf16x4 xv = *(const bf16x4*)(x + (size_t)row * D_ + t * 4);
  float f0 = (float)xv[0], f1 = (float)xv[1], f2 = (float)xv[2], f3 = (float)xv[3];
  float ss = f0 * f0 + f1 * f1 + f2 * f2 + f3 * f3;
#pragma unroll
  for (int m = 1; m < 64; m <<= 1) ss += __shfl_xor(ss, m, 64);
  __shared__ float red[4];
  if ((t & 63) == 0) red[t >> 6] = ss;
  __syncthreads();
  float tot = red[0] + red[1] + red[2] + red[3];
  float inv = rsqrtf(tot * (1.0f / D_) + EPSF);
  float4 wv = *(const float4*)(w + (size_t)c * D_ + t * 4);
  float4 bv = *(const float4*)(b + (size_t)c * D_ + t * 4);
  bf16x4 ov;
  ov[0] = (bf16)(wv.x * (f0 * inv) + bv.x);
  ov[1] = (bf16)(wv.y * (f1 * inv) + bv.y);
  ov[2] = (bf16)(wv.z * (f2 * inv) + bv.z);
  ov[3] = (bf16)(wv.w * (f3 * inv) + bv.w);
  *(bf16x4*)(out + (size_t)row * D_ + t * 4) = ov;
}

// ---------------- GEMM (m97 structure): C[m,n] = sum_k A[m,k] W[n,k] (+bias) (+R) ----------------
template <int BMt, int BNt, bool DUAL>
__global__ __launch_bounds__(256) void gemm_lds(const bf16* __restrict__ A,
                                                const bf16* __restrict__ W1,
                                                const bf16* __restrict__ W2,
                                                const float* __restrict__ b1,
                                                const float* __restrict__ b2,
                                                const bf16* __restrict__ R,
                                                bf16* __restrict__ O1,
                                                bf16* __restrict__ O2,
                                                int M, int N1, int K) {
  constexpr int MT = BMt / 32;
  constexpr int NT = BNt / 32;
  __shared__ bf16 sa[BMt * BK];
  __shared__ bf16 sb[BNt * BK];
  int t = threadIdx.x, l = t & 63, w = t >> 6;
  int m0 = blockIdx.y * BMt;
  int n0g = blockIdx.x * BNt;
  const bf16* W = (!DUAL || n0g < N1) ? W1 : W2;
  const float* bias = (!DUAL || n0g < N1) ? b1 : b2;
  bf16* Cout = (!DUAL || n0g < N1) ? O1 : O2;
  int n0 = DUAL ? (n0g & (N1 - 1)) : n0g;
  int wm = (w >> 1) * (BMt / 2), wn = (w & 1) * (BNt / 2);
  int lm = l & 15, lq = l >> 4;
  f32x4 acc[MT][NT] = {};

  for (int k0 = 0; k0 < K; k0 += BK) {
    __syncthreads();
#pragma unroll
    for (int p = 0; p < BMt / 64; ++p) {
      int lin = p * 256 + t;
      async16(A + (size_t)(m0 + (lin >> 2)) * K + k0 + (lin & 3) * 8, sa + lin * 8);
    }
#pragma unroll
    for (int p = 0; p < BNt / 64; ++p) {
      int lin = p * 256 + t;
      async16(W + (size_t)(n0 + (lin >> 2)) * K + k0 + (lin & 3) * 8, sb + lin * 8);
    }
    __syncthreads();
    bf16x8 af[MT], bfr[NT];
#pragma unroll
    for (int mt = 0; mt < MT; ++mt)
      af[mt] = *(const bf16x8*)(sa + (wm + mt * 16 + lm) * BK + lq * 8);
#pragma unroll
    for (int nt = 0; nt < NT; ++nt)
      bfr[nt] = *(const bf16x8*)(sb + (wn + nt * 16 + lm) * BK + lq * 8);
#pragma unroll
    for (int mt = 0; mt < MT; ++mt)
#pragma unroll
      for (int nt = 0; nt < NT; ++nt)
        acc[mt][nt] = mfma16(af[mt], bfr[nt], acc[mt][nt]);
  }
#pragma unroll
  for (int mt = 0; mt < MT; ++mt)
#pragma unroll
    for (int nt = 0; nt < NT; ++nt) {
      int col = n0 + wn + nt * 16 + lm;
      float bb = bias ? bias[col] : 0.0f;
#pragma unroll
      for (int r = 0; r < 4; ++r) {
        int row = m0 + wm + mt * 16 + lq * 4 + r;
        float v = acc[mt][nt][r] + bb;
        if (R) v += (float)R[(size_t)row * N1 + col];
        Cout[(size_t)row * N1 + col] = (bf16)v;
      }
    }
}

// ---------------- prep: RoPE (q,k -> qr,kr head-major) + V transpose, fused ----------------
__global__ __launch_bounds__(256) void prep_kernel(const bf16* __restrict__ qkv,
                                                   bf16* __restrict__ qr,
                                                   bf16* __restrict__ kr,
                                                   bf16* __restrict__ vt) {
  __shared__ bf16 tile[64][65];
  int t = threadIdx.x;
  int blk = blockIdx.x;  // B*H*(C/64)
  int ct = blk & 15;
  int h = (blk >> 4) & 15;
  int b = blk >> 8;
  int c0 = ct * 64;
  size_t hb = (size_t)((b * H_ + h) * C_);

  // --- RoPE: 2 passes x 32 rows; 8 threads/row, 8 elems (4 pairs) each ---
#pragma unroll
  for (int p = 0; p < 2; ++p) {
    int row = p * 32 + (t >> 3);
    int col = (t & 7) * 8;
    int c = c0 + row;
    size_t gq = (size_t)(b * C_ + c) * (3 * D_) + h * DH_ + col;
    bf16x8 qv = *(const bf16x8*)(qkv + gq);
    bf16x8 kv = *(const bf16x8*)(qkv + gq + D_);
    bf16x8 qo, ko;
#pragma unroll
    for (int j = 0; j < 4; ++j) {
      int i = (col >> 1) + j;  // pair index, theta = 10000^(-2(i-1)/64) per reference
      float theta = exp2f(-13.287712379549449f * (2.0f * ((float)i - 1.0f) / 64.0f));
      float ang = (float)c * theta;
      float sv = __sinf(ang), cv = __cosf(ang);
      float qe = (float)qv[2 * j], qo_ = (float)qv[2 * j + 1];
      float ke = (float)kv[2 * j], ko_ = (float)kv[2 * j + 1];
      qo[2 * j] = (bf16)(qe * cv + qo_ * sv);
      qo[2 * j + 1] = (bf16)(qo_ * cv - qe * sv);
      ko[2 * j] = (bf16)(ke * cv + ko_ * sv);
      ko[2 * j + 1] = (bf16)(ko_ * cv - ke * sv);
    }
    *(bf16x8*)(qr + (hb + c) * DH_ + col) = qo;
    *(bf16x8*)(kr + (hb + c) * DH_ + col) = ko;
  }

  // --- V transpose into vt[b][h][dh][c] ---
#pragma unroll
  for (int p = 0; p < 16; ++p) {
    int lin = p * 256 + t;
    int cl = lin >> 6, dh = lin & 63;
    tile[dh][cl] = qkv[(size_t)(b * C_ + c0 + cl) * (3 * D_) + 2 * D_ + h * DH_ + dh];
  }
  __syncthreads();
  size_t vbase = (size_t)((b * H_ + h) * DH_) * C_;
#pragma unroll
  for (int p = 0; p < 16; ++p) {
    int lin = p * 256 + t;
    int dh = lin >> 6, cl = lin & 63;
    vt[vbase + (size_t)dh * C_ + c0 + cl] = tile[dh][cl];
  }
}

// ---------------- Fused attention, software-pipelined LDS staging ----------------
__global__ __launch_bounds__(256) void attn_kernel(const bf16* __restrict__ qkv,
                                                   const bf16* __restrict__ qr,
                                                   const bf16* __restrict__ kr,
                                                   const bf16* __restrict__ vt,
                                                   bf16* __restrict__ y) {
  __shared__ bf16 sk[64 * 72];     // unrotated K tile [j][dh]
  __shared__ bf16 skr[64 * 72];    // rotated K tile  [j][dh]
  __shared__ bf16 sv[64 * 72];     // V^T tile        [dh][j]
  __shared__ bf16 pl[4][16 * 72];  // per-wave P tile [i][j]
  int t = threadIdx.x, l = t & 63, w = t >> 6;
  int blk = blockIdx.x;  // B*H*(C/64)
  int it = blk & 15;
  int h = (blk >> 4) & 15;
  int b = blk >> 8;
  int i_base = it * 64 + w * 16;
  int lm = l & 15, lq = l >> 4;
  const float scale = 0.125f;

  size_t hq = (size_t)h * DH_;
  size_t qrow = (size_t)(b * C_ + i_base + lm) * (3 * D_) + hq;
  size_t hb = (size_t)((b * H_ + h) * C_);
  bf16x8 qp[2], qrf[2];
#pragma unroll
  for (int kk = 0; kk < 2; ++kk) {
    qp[kk] = *(const bf16x8*)(qkv + qrow + kk * 32 + lq * 8);
    qrf[kk] = *(const bf16x8*)(qr + (hb + i_base + lm) * DH_ + kk * 32 + lq * 8);
  }

  float den[4] = {0.f, 0.f, 0.f, 0.f};
  f32x4 yacc[4] = {};
  int i_max = i_base + 15;
  size_t kbase = (size_t)(b * C_) * (3 * D_) + D_ + hq;
  size_t krbase = hb * DH_;
  size_t vtbase = (size_t)((b * H_ + h) * DH_) * C_;
  int sr = t >> 3;       // 0..31 (row within staging pass)
  int sc = (t & 7) * 8;  // 0..56 (col, elems)

  int4 pk[2], pkr[2], pv[2];
  auto fetch = [&](int j0) {
#pragma unroll
    for (int p = 0; p < 2; ++p) {
      int jr = p * 32 + sr;
      pk[p] = *(const int4*)(qkv + kbase + (size_t)(j0 + jr) * (3 * D_) + sc);
      pkr[p] = *(const int4*)(kr + krbase + (size_t)(j0 + jr) * DH_ + sc);
      pv[p] = *(const int4*)(vt + vtbase + (size_t)jr * C_ + j0 + sc);
    }
  };
  fetch(0);

  for (int j0 = 0; j0 < C_; j0 += 64) {
    __syncthreads();  // prior iter's tile reads done
#pragma unroll
    for (int p = 0; p < 2; ++p) {
      int jr = p * 32 + sr;
      *(int4*)(sk + jr * 72 + sc) = pk[p];
      *(int4*)(skr + jr * 72 + sc) = pkr[p];
      *(int4*)(sv + jr * 72 + sc) = pv[p];
    }
    __syncthreads();
    if (j0 + 64 < C_) fetch(j0 + 64);  // prefetch next tile; latency overlaps compute below
    // denominator: all j, unrotated q.k
#pragma unroll
    for (int js = 0; js < 64; js += 16) {
      bf16x8 kf0 = *(const bf16x8*)(sk + (js + lm) * 72 + lq * 8);
      bf16x8 kf1 = *(const bf16x8*)(sk + (js + lm) * 72 + 32 + lq * 8);
      f32x4 s = {0.f, 0.f, 0.f, 0.f};
      s = mfma16(qp[0], kf0, s);
      s = mfma16(qp[1], kf1, s);
#pragma unroll
      for (int r = 0; r < 4; ++r) den[r] += __expf(s[r] * scale);
    }
    // numerator + PV: only tiles intersecting the causal triangle (wave-uniform guard)
    if (j0 <= i_max) {
#pragma unroll
      for (int js = 0; js < 64; js += 16) {
        bf16x8 kf0 = *(const bf16x8*)(skr + (js + lm) * 72 + lq * 8);
        bf16x8 kf1 = *(const bf16x8*)(skr + (js + lm) * 72 + 32 + lq * 8);
        f32x4 s = {0.f, 0.f, 0.f, 0.f};
        s = mfma16(qrf[0], kf0, s);
        s = mfma16(qrf[1], kf1, s);
#pragma unroll
        for (int r = 0; r < 4; ++r) {
          int jg = j0 + js + lm;
          int ig = i_base + lq * 4 + r;
          float p = (jg <= ig) ? __expf(s[r] * scale) : 0.0f;
          pl[w][(lq * 4 + r) * 72 + js + lm] = (bf16)p;
        }
      }
      __builtin_amdgcn_wave_barrier();
      bf16x8 pf0 = *(const bf16x8*)(pl[w] + lm * 72 + lq * 8);
      bf16x8 pf1 = *(const bf16x8*)(pl[w] + lm * 72 + 32 + lq * 8);
#pragma unroll
      for (int tt = 0; tt < 4; ++tt) {
        bf16x8 vf0 = *(const bf16x8*)(sv + (tt * 16 + lm) * 72 + lq * 8);
        bf16x8 vf1 = *(const bf16x8*)(sv + (tt * 16 + lm) * 72 + 32 + lq * 8);
        yacc[tt] = mfma16(pf0, vf0, mfma16(pf1, vf1, yacc[tt]));
      }
      __builtin_amdgcn_wave_barrier();
    }
  }
  float inv[4];
#pragma unroll
  for (int r = 0; r < 4; ++r) {
    float d = den[r];
    d += __shfl_xor(d, 1, 64);
    d += __shfl_xor(d, 2, 64);
    d += __shfl_xor(d, 4, 64);
    d += __shfl_xor(d, 8, 64);
    inv[r] = 1.0f / d;
  }
#pragma unroll
  for (int tt = 0; tt < 4; ++tt)
#pragma unroll
    for (int r = 0; r < 4; ++r) {
      int ig = i_base + lq * 4 + r;
      y[(size_t)(b * C_ + ig) * D_ + hq + tt * 16 + lm] = (bf16)(yacc[tt][r] * inv[r]);
    }
}

// ---------------- FFN gate epilogue: out = x3 + (wx*sigmoid(beta*wx))*hv (fp32 out) ----------------
__global__ __launch_bounds__(256) void ffn_final_kernel(const bf16* __restrict__ x3,
                                                        const bf16* __restrict__ wx,
                                                        const bf16* __restrict__ hv,
                                                        const float* __restrict__ beta_p,
                                                        float* __restrict__ out, int n) {
  int idx = blockIdx.x * 256 + threadIdx.x;
  if (idx >= n) return;
  float beta = beta_p[0];
  float z = (float)wx[idx];
  float sw = z / (1.0f + __expf(-beta * z));
  out[idx] = (float)x3[idx] + sw * (float)hv[idx];
}

extern "C" void kernel_launch(void* const* d_in, const int* in_sizes, int n_in,
                              void* d_out, int out_size, void* d_ws, size_t ws_size,
                              hipStream_t stream) {
  const float* x = (const float*)d_in[0];
  const float* rms_w = (const float*)d_in[1];
  const float* rms_b = (const float*)d_in[2];
  const float* Wqkv = (const float*)d_in[3];
  const float* Wout = (const float*)d_in[4];
  const float* bout = (const float*)d_in[5];
  const float* Wf = (const float*)d_in[6];
  const float* bfp = (const float*)d_in[7];
  const float* Ww = (const float*)d_in[8];
  const float* bw = (const float*)d_in[9];
  const float* Wv = (const float*)d_in[10];
  const float* bv = (const float*)d_in[11];
  const float* beta = (const float*)d_in[12];
  float* out = (float*)d_out;

  // Workspace (bf16 elems), M1 = 2M elems. Peak live = 7*M1 = 28 MB (proven size).
  bf16* ws = (bf16*)d_ws;
  const size_t MC = (size_t)B_ * C_;  // 2048
  const size_t M1 = MC * D_;          // 2,097,152 elems
  bf16* x1 = ws + 0 * M1;             // [0,1)M1
  bf16* qkv = ws + 1 * M1;            // [1,4)M1
  bf16* qr = ws + 4 * M1;             // [4,5)M1
  bf16* kr = ws + 5 * M1;             // [5,6)M1
  bf16* vt = ws + 6 * M1;             // [6,7)M1
  bf16* y = (bf16*)d_out;             // 4 MB bf16 inside 8 MB fp32 d_out; dead before final write
  // phase-scoped aliases (regions dead at time of use):
  bf16* Wqkv_bf = ws + 4 * M1;        // 1.5*M1; lives only during GEMM1 (qr/kr written later)
  bf16* W4 = ws + 1 * M1;             // 4 x 0.5*M1 slots (qkv dead post-attn): Wout,Wf,Ww,Wv
  bf16* x2 = ws + 4 * M1;
  bf16* x3 = ws + 5 * M1;
  bf16* hbuf = ws + 6 * M1;
  bf16* wx = ws + 3 * M1;             // upper qkv region (dead post-attn, above W4 slots)
  bf16* hv = ws + 0 * M1;             // x1 region (dead after gemm2 consumed the residual)

  rmsnorm_f32_kernel<<<MC, 256, 0, stream>>>(x, rms_w, rms_b, x1);
  cvt_kernel<<<(3 * D_ * D_) / 1024, 256, 0, stream>>>(Wqkv, Wqkv_bf);
  gemm_lds<128, 64, false><<<dim3(3 * D_ / 64, MC / 128), 256, 0, stream>>>(
      x1, Wqkv_bf, nullptr, nullptr, nullptr, nullptr, qkv, nullptr, MC, 3 * D_, D_);
  prep_kernel<<<B_ * H_ * (C_ / 64), 256, 0, stream>>>(qkv, qr, kr, vt);
  attn_kernel<<<B_ * H_ * (C_ / 64), 256, 0, stream>>>(qkv, qr, kr, vt, y);
  cvt4_kernel<<<4 * (D_ * D_) / 1024, 256, 0, stream>>>(Wout, Wf, Ww, Wv, W4);
  gemm_lds<64, 64, false><<<dim3(D_ / 64, MC / 64), 256, 0, stream>>>(
      y, W4, nullptr, bout, nullptr, x1, x2, nullptr, MC, D_, D_);
  rmsnorm_bf16_kernel<<<MC, 256, 0, stream>>>(x2, rms_w, rms_b, x3);
  gemm_lds<64, 64, false><<<dim3(D_ / 64, MC / 64), 256, 0, stream>>>(
      x3, W4 + (size_t)(D_ * D_), nullptr, bfp, nullptr, nullptr, hbuf, MC ? hbuf : nullptr, MC, D_, D_);
  gemm_lds<64, 64, true><<<dim3(2 * D_ / 64, MC / 64), 256, 0, stream>>>(
      hbuf, W4 + 2 * (size_t)(D_ * D_), W4 + 3 * (size_t)(D_ * D_), bw, bv, nullptr, wx, hv,
      MC, D_, D_);
  ffn_final_kernel<<<(int)((MC * D_) / 256), 256, 0, stream>>>(x3, wx, hv, beta, out,
                                                               (int)(MC * D_));
}

// Round 7
// 234.846 us; speedup vs baseline: 1.6290x; 1.1463x over previous
//
#include <hip/hip_runtime.h>
#include <math.h>

#define B_ 2
#define C_ 1024
#define D_ 1024
#define H_ 16
#define DH_ 64
#define EPSF 1e-8f
#define BK 32

typedef __bf16 bf16;
typedef __attribute__((ext_vector_type(4))) __bf16 bf16x4;
typedef __attribute__((ext_vector_type(8))) __bf16 bf16x8;
typedef __attribute__((ext_vector_type(4))) float f32x4;

__device__ inline f32x4 mfma16(bf16x8 a, bf16x8 b, f32x4 c) {
  return __builtin_amdgcn_mfma_f32_16x16x32_bf16(a, b, c, 0, 0, 0);
}

// async global->LDS, 16B per lane. LDS dest contract: wave-uniform base + lane*16.
__device__ inline void async16(const bf16* g, bf16* l) {
  __builtin_amdgcn_global_load_lds((const __attribute__((address_space(1))) void*)g,
                                   (__attribute__((address_space(3))) void*)l, 16, 0, 0);
}

// ---------------- fp32 -> bf16 convert, single weight (QKV) ----------------
__global__ __launch_bounds__(256) void cvt_kernel(const float* __restrict__ src,
                                                  bf16* __restrict__ dst) {
  int idx = (blockIdx.x * 256 + threadIdx.x) * 4;
  float4 v = *(const float4*)(src + idx);
  bf16x4 o;
  o[0] = (bf16)v.x; o[1] = (bf16)v.y; o[2] = (bf16)v.z; o[3] = (bf16)v.w;
  *(bf16x4*)(dst + idx) = o;
}

// ---------------- fp32 -> bf16 convert, 4 weights to contiguous slots ----------------
__global__ __launch_bounds__(256) void cvt4_kernel(const float* __restrict__ s0,
                                                   const float* __restrict__ s1,
                                                   const float* __restrict__ s2,
                                                   const float* __restrict__ s3,
                                                   bf16* __restrict__ dst) {
  int which = blockIdx.x >> 10;  // D*D/1024 = 1024 blocks per weight
  int local = (blockIdx.x & 1023) * 1024 + threadIdx.x * 4;
  const float* src = which == 0 ? s0 : which == 1 ? s1 : which == 2 ? s2 : s3;
  float4 v = *(const float4*)(src + local);
  bf16x4 o;
  o[0] = (bf16)v.x; o[1] = (bf16)v.y; o[2] = (bf16)v.z; o[3] = (bf16)v.w;
  *(bf16x4*)(dst + (size_t)which * (D_ * D_) + local) = o;
}

// ---------------- RMSNorm (fp32 in, bf16 out) ----------------
__global__ __launch_bounds__(256) void rmsnorm_f32_kernel(const float* __restrict__ x,
                                                          const float* __restrict__ w,
                                                          const float* __restrict__ b,
                                                          bf16* __restrict__ out) {
  int row = blockIdx.x;
  int c = row & (C_ - 1);
  int t = threadIdx.x;
  float4 xv = *(const float4*)(x + (size_t)row * D_ + t * 4);
  float ss = xv.x * xv.x + xv.y * xv.y + xv.z * xv.z + xv.w * xv.w;
#pragma unroll
  for (int m = 1; m < 64; m <<= 1) ss += __shfl_xor(ss, m, 64);
  __shared__ float red[4];
  if ((t & 63) == 0) red[t >> 6] = ss;
  __syncthreads();
  float tot = red[0] + red[1] + red[2] + red[3];
  float inv = rsqrtf(tot * (1.0f / D_) + EPSF);
  float4 wv = *(const float4*)(w + (size_t)c * D_ + t * 4);
  float4 bv = *(const float4*)(b + (size_t)c * D_ + t * 4);
  bf16x4 ov;
  ov[0] = (bf16)(wv.x * (xv.x * inv) + bv.x);
  ov[1] = (bf16)(wv.y * (xv.y * inv) + bv.y);
  ov[2] = (bf16)(wv.z * (xv.z * inv) + bv.z);
  ov[3] = (bf16)(wv.w * (xv.w * inv) + bv.w);
  *(bf16x4*)(out + (size_t)row * D_ + t * 4) = ov;
}

// ---------------- RMSNorm (bf16 in, bf16 out) ----------------
__global__ __launch_bounds__(256) void rmsnorm_bf16_kernel(const bf16* __restrict__ x,
                                                           const float* __restrict__ w,
                                                           const float* __restrict__ b,
                                                           bf16* __restrict__ out) {
  int row = blockIdx.x;
  int c = row & (C_ - 1);
  int t = threadIdx.x;
  bf16x4 xv = *(const bf16x4*)(x + (size_t)row * D_ + t * 4);
  float f0 = (float)xv[0], f1 = (float)xv[1], f2 = (float)xv[2], f3 = (float)xv[3];
  float ss = f0 * f0 + f1 * f1 + f2 * f2 + f3 * f3;
#pragma unroll
  for (int m = 1; m < 64; m <<= 1) ss += __shfl_xor(ss, m, 64);
  __shared__ float red[4];
  if ((t & 63) == 0) red[t >> 6] = ss;
  __syncthreads();
  float tot = red[0] + red[1] + red[2] + red[3];
  float inv = rsqrtf(tot * (1.0f / D_) + EPSF);
  float4 wv = *(const float4*)(w + (size_t)c * D_ + t * 4);
  float4 bv = *(const float4*)(b + (size_t)c * D_ + t * 4);
  bf16x4 ov;
  ov[0] = (bf16)(wv.x * (f0 * inv) + bv.x);
  ov[1] = (bf16)(wv.y * (f1 * inv) + bv.y);
  ov[2] = (bf16)(wv.z * (f2 * inv) + bv.z);
  ov[3] = (bf16)(wv.w * (f3 * inv) + bv.w);
  *(bf16x4*)(out + (size_t)row * D_ + t * 4) = ov;
}

// ---------------- GEMM (m97 structure): C[m,n] = sum_k A[m,k] W[n,k] (+bias) (+R) ----------------
template <int BMt, int BNt, bool DUAL>
__global__ __launch_bounds__(256) void gemm_lds(const bf16* __restrict__ A,
                                                const bf16* __restrict__ W1,
                                                const bf16* __restrict__ W2,
                                                const float* __restrict__ b1,
                                                const float* __restrict__ b2,
                                                const bf16* __restrict__ R,
                                                bf16* __restrict__ O1,
                                                bf16* __restrict__ O2,
                                                int M, int N1, int K) {
  constexpr int MT = BMt / 32;
  constexpr int NT = BNt / 32;
  __shared__ bf16 sa[BMt * BK];
  __shared__ bf16 sb[BNt * BK];
  int t = threadIdx.x, l = t & 63, w = t >> 6;
  int m0 = blockIdx.y * BMt;
  int n0g = blockIdx.x * BNt;
  const bf16* W = (!DUAL || n0g < N1) ? W1 : W2;
  const float* bias = (!DUAL || n0g < N1) ? b1 : b2;
  bf16* Cout = (!DUAL || n0g < N1) ? O1 : O2;
  int n0 = DUAL ? (n0g & (N1 - 1)) : n0g;
  int wm = (w >> 1) * (BMt / 2), wn = (w & 1) * (BNt / 2);
  int lm = l & 15, lq = l >> 4;
  f32x4 acc[MT][NT] = {};

  for (int k0 = 0; k0 < K; k0 += BK) {
    __syncthreads();
#pragma unroll
    for (int p = 0; p < BMt / 64; ++p) {
      int lin = p * 256 + t;
      async16(A + (size_t)(m0 + (lin >> 2)) * K + k0 + (lin & 3) * 8, sa + lin * 8);
    }
#pragma unroll
    for (int p = 0; p < BNt / 64; ++p) {
      int lin = p * 256 + t;
      async16(W + (size_t)(n0 + (lin >> 2)) * K + k0 + (lin & 3) * 8, sb + lin * 8);
    }
    __syncthreads();
    bf16x8 af[MT], bfr[NT];
#pragma unroll
    for (int mt = 0; mt < MT; ++mt)
      af[mt] = *(const bf16x8*)(sa + (wm + mt * 16 + lm) * BK + lq * 8);
#pragma unroll
    for (int nt = 0; nt < NT; ++nt)
      bfr[nt] = *(const bf16x8*)(sb + (wn + nt * 16 + lm) * BK + lq * 8);
#pragma unroll
    for (int mt = 0; mt < MT; ++mt)
#pragma unroll
      for (int nt = 0; nt < NT; ++nt)
        acc[mt][nt] = mfma16(af[mt], bfr[nt], acc[mt][nt]);
  }
#pragma unroll
  for (int mt = 0; mt < MT; ++mt)
#pragma unroll
    for (int nt = 0; nt < NT; ++nt) {
      int col = n0 + wn + nt * 16 + lm;
      float bb = bias ? bias[col] : 0.0f;
#pragma unroll
      for (int r = 0; r < 4; ++r) {
        int row = m0 + wm + mt * 16 + lq * 4 + r;
        float v = acc[mt][nt][r] + bb;
        if (R) v += (float)R[(size_t)row * N1 + col];
        Cout[(size_t)row * N1 + col] = (bf16)v;
      }
    }
}

// ---------------- prep: RoPE (q,k -> qr,kr head-major) + V transpose, fused ----------------
__global__ __launch_bounds__(256) void prep_kernel(const bf16* __restrict__ qkv,
                                                   bf16* __restrict__ qr,
                                                   bf16* __restrict__ kr,
                                                   bf16* __restrict__ vt) {
  __shared__ bf16 tile[64][65];
  int t = threadIdx.x;
  int blk = blockIdx.x;  // B*H*(C/64)
  int ct = blk & 15;
  int h = (blk >> 4) & 15;
  int b = blk >> 8;
  int c0 = ct * 64;
  size_t hb = (size_t)((b * H_ + h) * C_);

#pragma unroll
  for (int p = 0; p < 2; ++p) {
    int row = p * 32 + (t >> 3);
    int col = (t & 7) * 8;
    int c = c0 + row;
    size_t gq = (size_t)(b * C_ + c) * (3 * D_) + h * DH_ + col;
    bf16x8 qv = *(const bf16x8*)(qkv + gq);
    bf16x8 kv = *(const bf16x8*)(qkv + gq + D_);
    bf16x8 qo, ko;
#pragma unroll
    for (int j = 0; j < 4; ++j) {
      int i = (col >> 1) + j;  // pair index, theta = 10000^(-2(i-1)/64) per reference
      float theta = exp2f(-13.287712379549449f * (2.0f * ((float)i - 1.0f) / 64.0f));
      float ang = (float)c * theta;
      float sv = __sinf(ang), cv = __cosf(ang);
      float qe = (float)qv[2 * j], qo_ = (float)qv[2 * j + 1];
      float ke = (float)kv[2 * j], ko_ = (float)kv[2 * j + 1];
      qo[2 * j] = (bf16)(qe * cv + qo_ * sv);
      qo[2 * j + 1] = (bf16)(qo_ * cv - qe * sv);
      ko[2 * j] = (bf16)(ke * cv + ko_ * sv);
      ko[2 * j + 1] = (bf16)(ko_ * cv - ke * sv);
    }
    *(bf16x8*)(qr + (hb + c) * DH_ + col) = qo;
    *(bf16x8*)(kr + (hb + c) * DH_ + col) = ko;
  }

#pragma unroll
  for (int p = 0; p < 16; ++p) {
    int lin = p * 256 + t;
    int cl = lin >> 6, dh = lin & 63;
    tile[dh][cl] = qkv[(size_t)(b * C_ + c0 + cl) * (3 * D_) + 2 * D_ + h * DH_ + dh];
  }
  __syncthreads();
  size_t vbase = (size_t)((b * H_ + h) * DH_) * C_;
#pragma unroll
  for (int p = 0; p < 16; ++p) {
    int lin = p * 256 + t;
    int dh = lin >> 6, cl = lin & 63;
    vt[vbase + (size_t)dh * C_ + c0 + cl] = tile[dh][cl];
  }
}

// ---------------- Fused attention, software-pipelined (scalar prefetch regs) ----------------
__global__ __launch_bounds__(256) void attn_kernel(const bf16* __restrict__ qkv,
                                                   const bf16* __restrict__ qr,
                                                   const bf16* __restrict__ kr,
                                                   const bf16* __restrict__ vt,
                                                   bf16* __restrict__ y) {
  __shared__ bf16 sk[64 * 72];     // unrotated K tile [j][dh]
  __shared__ bf16 skr[64 * 72];    // rotated K tile  [j][dh]
  __shared__ bf16 sv[64 * 72];     // V^T tile        [dh][j]
  __shared__ bf16 pl[4][16 * 72];  // per-wave P tile [i][j]
  int t = threadIdx.x, l = t & 63, w = t >> 6;
  int blk = blockIdx.x;  // B*H*(C/64)
  int it = blk & 15;
  int h = (blk >> 4) & 15;
  int b = blk >> 8;
  int i_base = it * 64 + w * 16;
  int lm = l & 15, lq = l >> 4;
  const float scale = 0.125f;

  size_t hq = (size_t)h * DH_;
  size_t qrow = (size_t)(b * C_ + i_base + lm) * (3 * D_) + hq;
  size_t hb = (size_t)((b * H_ + h) * C_);
  bf16x8 qp[2], qrf[2];
#pragma unroll
  for (int kk = 0; kk < 2; ++kk) {
    qp[kk] = *(const bf16x8*)(qkv + qrow + kk * 32 + lq * 8);
    qrf[kk] = *(const bf16x8*)(qr + (hb + i_base + lm) * DH_ + kk * 32 + lq * 8);
  }

  float den[4] = {0.f, 0.f, 0.f, 0.f};
  f32x4 yacc[4] = {};
  int i_max = i_base + 15;
  size_t kbase = (size_t)(b * C_) * (3 * D_) + D_ + hq;
  size_t krbase = hb * DH_;
  size_t vtbase = (size_t)((b * H_ + h) * DH_) * C_;
  int sr = t >> 3;       // 0..31 (row within staging pass)
  int sc = (t & 7) * 8;  // 0..56 (col, elems)

  // Prefetch registers: NAMED SCALARS ONLY (arrays/lambda in round 6 went to scratch:
  // WRITE_SIZE 103 MB of spill traffic; scalars are guaranteed VGPR-resident).
  int4 pk0, pk1, pkr0, pkr1, pv0, pv1;
#define FETCH_TILE(J0)                                                               \
  pk0 = *(const int4*)(qkv + kbase + (size_t)((J0) + sr) * (3 * D_) + sc);           \
  pk1 = *(const int4*)(qkv + kbase + (size_t)((J0) + 32 + sr) * (3 * D_) + sc);      \
  pkr0 = *(const int4*)(kr + krbase + (size_t)((J0) + sr) * DH_ + sc);               \
  pkr1 = *(const int4*)(kr + krbase + (size_t)((J0) + 32 + sr) * DH_ + sc);          \
  pv0 = *(const int4*)(vt + vtbase + (size_t)sr * C_ + (J0) + sc);                   \
  pv1 = *(const int4*)(vt + vtbase + (size_t)(32 + sr) * C_ + (J0) + sc);

  FETCH_TILE(0)

  for (int j0 = 0; j0 < C_; j0 += 64) {
    __syncthreads();  // prior iter's tile reads done
    *(int4*)(sk + sr * 72 + sc) = pk0;
    *(int4*)(sk + (32 + sr) * 72 + sc) = pk1;
    *(int4*)(skr + sr * 72 + sc) = pkr0;
    *(int4*)(skr + (32 + sr) * 72 + sc) = pkr1;
    *(int4*)(sv + sr * 72 + sc) = pv0;
    *(int4*)(sv + (32 + sr) * 72 + sc) = pv1;
    __syncthreads();
    if (j0 + 64 < C_) {
      FETCH_TILE(j0 + 64)  // latency overlaps the MFMA/exp work below
    }
    // denominator: all j, unrotated q.k
#pragma unroll
    for (int js = 0; js < 64; js += 16) {
      bf16x8 kf0 = *(const bf16x8*)(sk + (js + lm) * 72 + lq * 8);
      bf16x8 kf1 = *(const bf16x8*)(sk + (js + lm) * 72 + 32 + lq * 8);
      f32x4 s = {0.f, 0.f, 0.f, 0.f};
      s = mfma16(qp[0], kf0, s);
      s = mfma16(qp[1], kf1, s);
#pragma unroll
      for (int r = 0; r < 4; ++r) den[r] += __expf(s[r] * scale);
    }
    // numerator + PV: only tiles intersecting the causal triangle (wave-uniform guard)
    if (j0 <= i_max) {
#pragma unroll
      for (int js = 0; js < 64; js += 16) {
        bf16x8 kf0 = *(const bf16x8*)(skr + (js + lm) * 72 + lq * 8);
        bf16x8 kf1 = *(const bf16x8*)(skr + (js + lm) * 72 + 32 + lq * 8);
        f32x4 s = {0.f, 0.f, 0.f, 0.f};
        s = mfma16(qrf[0], kf0, s);
        s = mfma16(qrf[1], kf1, s);
#pragma unroll
        for (int r = 0; r < 4; ++r) {
          int jg = j0 + js + lm;
          int ig = i_base + lq * 4 + r;
          float p = (jg <= ig) ? __expf(s[r] * scale) : 0.0f;
          pl[w][(lq * 4 + r) * 72 + js + lm] = (bf16)p;
        }
      }
      __builtin_amdgcn_wave_barrier();
      bf16x8 pf0 = *(const bf16x8*)(pl[w] + lm * 72 + lq * 8);
      bf16x8 pf1 = *(const bf16x8*)(pl[w] + lm * 72 + 32 + lq * 8);
#pragma unroll
      for (int tt = 0; tt < 4; ++tt) {
        bf16x8 vf0 = *(const bf16x8*)(sv + (tt * 16 + lm) * 72 + lq * 8);
        bf16x8 vf1 = *(const bf16x8*)(sv + (tt * 16 + lm) * 72 + 32 + lq * 8);
        yacc[tt] = mfma16(pf0, vf0, mfma16(pf1, vf1, yacc[tt]));
      }
      __builtin_amdgcn_wave_barrier();
    }
  }
#undef FETCH_TILE
  float inv[4];
#pragma unroll
  for (int r = 0; r < 4; ++r) {
    float d = den[r];
    d += __shfl_xor(d, 1, 64);
    d += __shfl_xor(d, 2, 64);
    d += __shfl_xor(d, 4, 64);
    d += __shfl_xor(d, 8, 64);
    inv[r] = 1.0f / d;
  }
#pragma unroll
  for (int tt = 0; tt < 4; ++tt)
#pragma unroll
    for (int r = 0; r < 4; ++r) {
      int ig = i_base + lq * 4 + r;
      y[(size_t)(b * C_ + ig) * D_ + hq + tt * 16 + lm] = (bf16)(yacc[tt][r] * inv[r]);
    }
}

// ---------------- FFN gate epilogue: out = x3 + (wx*sigmoid(beta*wx))*hv (fp32 out) ----------------
__global__ __launch_bounds__(256) void ffn_final_kernel(const bf16* __restrict__ x3,
                                                        const bf16* __restrict__ wx,
                                                        const bf16* __restrict__ hv,
                                                        const float* __restrict__ beta_p,
                                                        float* __restrict__ out, int n) {
  int idx = blockIdx.x * 256 + threadIdx.x;
  if (idx >= n) return;
  float beta = beta_p[0];
  float z = (float)wx[idx];
  float sw = z / (1.0f + __expf(-beta * z));
  out[idx] = (float)x3[idx] + sw * (float)hv[idx];
}

extern "C" void kernel_launch(void* const* d_in, const int* in_sizes, int n_in,
                              void* d_out, int out_size, void* d_ws, size_t ws_size,
                              hipStream_t stream) {
  const float* x = (const float*)d_in[0];
  const float* rms_w = (const float*)d_in[1];
  const float* rms_b = (const float*)d_in[2];
  const float* Wqkv = (const float*)d_in[3];
  const float* Wout = (const float*)d_in[4];
  const float* bout = (const float*)d_in[5];
  const float* Wf = (const float*)d_in[6];
  const float* bfp = (const float*)d_in[7];
  const float* Ww = (const float*)d_in[8];
  const float* bw = (const float*)d_in[9];
  const float* Wv = (const float*)d_in[10];
  const float* bv = (const float*)d_in[11];
  const float* beta = (const float*)d_in[12];
  float* out = (float*)d_out;

  // Workspace (bf16 elems), M1 = 2M elems. Peak live = 7*M1 = 28 MB (proven size).
  bf16* ws = (bf16*)d_ws;
  const size_t MC = (size_t)B_ * C_;  // 2048
  const size_t M1 = MC * D_;          // 2,097,152 elems
  bf16* x1 = ws + 0 * M1;             // [0,1)M1
  bf16* qkv = ws + 1 * M1;            // [1,4)M1
  bf16* qr = ws + 4 * M1;             // [4,5)M1
  bf16* kr = ws + 5 * M1;             // [5,6)M1
  bf16* vt = ws + 6 * M1;             // [6,7)M1
  bf16* y = (bf16*)d_out;             // 4 MB bf16 inside 8 MB fp32 d_out; dead before final write
  // phase-scoped aliases (regions dead at time of use):
  bf16* Wqkv_bf = ws + 4 * M1;        // 1.5*M1; lives only during GEMM1 (qr/kr written later)
  bf16* W4 = ws + 1 * M1;             // 4 x 0.5*M1 slots (qkv dead post-attn): Wout,Wf,Ww,Wv
  bf16* x2 = ws + 4 * M1;
  bf16* x3 = ws + 5 * M1;
  bf16* hbuf = ws + 6 * M1;
  bf16* wx = ws + 3 * M1;             // upper qkv region (dead post-attn, above W4 slots)
  bf16* hv = ws + 0 * M1;             // x1 region (dead after gemm2 consumed the residual)

  rmsnorm_f32_kernel<<<MC, 256, 0, stream>>>(x, rms_w, rms_b, x1);
  cvt_kernel<<<(3 * D_ * D_) / 1024, 256, 0, stream>>>(Wqkv, Wqkv_bf);
  gemm_lds<128, 64, false><<<dim3(3 * D_ / 64, MC / 128), 256, 0, stream>>>(
      x1, Wqkv_bf, nullptr, nullptr, nullptr, nullptr, qkv, nullptr, MC, 3 * D_, D_);
  prep_kernel<<<B_ * H_ * (C_ / 64), 256, 0, stream>>>(qkv, qr, kr, vt);
  attn_kernel<<<B_ * H_ * (C_ / 64), 256, 0, stream>>>(qkv, qr, kr, vt, y);
  cvt4_kernel<<<4 * (D_ * D_) / 1024, 256, 0, stream>>>(Wout, Wf, Ww, Wv, W4);
  gemm_lds<64, 64, false><<<dim3(D_ / 64, MC / 64), 256, 0, stream>>>(
      y, W4, nullptr, bout, nullptr, x1, x2, nullptr, MC, D_, D_);
  rmsnorm_bf16_kernel<<<MC, 256, 0, stream>>>(x2, rms_w, rms_b, x3);
  gemm_lds<64, 64, false><<<dim3(D_ / 64, MC / 64), 256, 0, stream>>>(
      x3, W4 + (size_t)(D_ * D_), nullptr, bfp, nullptr, nullptr, hbuf, nullptr, MC, D_, D_);
  gemm_lds<64, 64, true><<<dim3(2 * D_ / 64, MC / 64), 256, 0, stream>>>(
      hbuf, W4 + 2 * (size_t)(D_ * D_), W4 + 3 * (size_t)(D_ * D_), bw, bv, nullptr, wx, hv,
      MC, D_, D_);
  ffn_final_kernel<<<(int)((MC * D_) / 256), 256, 0, stream>>>(x3, wx, hv, beta, out,
                                                               (int)(MC * D_));
}

// Round 8
// 233.805 us; speedup vs baseline: 1.6362x; 1.0045x over previous
//
#include <hip/hip_runtime.h>
#include <math.h>

#define B_ 2
#define C_ 1024
#define D_ 1024
#define H_ 16
#define DH_ 64
#define EPSF 1e-8f
#define BK 32

typedef __bf16 bf16;
typedef __attribute__((ext_vector_type(4))) __bf16 bf16x4;
typedef __attribute__((ext_vector_type(8))) __bf16 bf16x8;
typedef __attribute__((ext_vector_type(4))) float f32x4;

__device__ inline f32x4 mfma16(bf16x8 a, bf16x8 b, f32x4 c) {
  return __builtin_amdgcn_mfma_f32_16x16x32_bf16(a, b, c, 0, 0, 0);
}

// async global->LDS, 16B per lane. LDS dest contract: wave-uniform base + lane*16.
__device__ inline void async16(const bf16* g, bf16* l) {
  __builtin_amdgcn_global_load_lds((const __attribute__((address_space(1))) void*)g,
                                   (__attribute__((address_space(3))) void*)l, 16, 0, 0);
}

// ---------------- fp32 -> bf16: ALL weights in one launch ----------------
// segments of D*D elems: 0-2 = Wqkv, 3 = Wout, 4 = Wf, 5 = Ww, 6 = Wv
__global__ __launch_bounds__(256) void cvt_all_kernel(const float* __restrict__ wqkv,
                                                      const float* __restrict__ wout,
                                                      const float* __restrict__ wf,
                                                      const float* __restrict__ www,
                                                      const float* __restrict__ wv,
                                                      bf16* __restrict__ dst) {
  int seg = blockIdx.x >> 10;  // 1024 blocks per D*D segment
  int local = (blockIdx.x & 1023) * 1024 + threadIdx.x * 4;
  const float* src = seg < 3 ? wqkv + (size_t)seg * (D_ * D_)
                   : seg == 3 ? wout : seg == 4 ? wf : seg == 5 ? www : wv;
  float4 v = *(const float4*)(src + local);
  bf16x4 o;
  o[0] = (bf16)v.x; o[1] = (bf16)v.y; o[2] = (bf16)v.z; o[3] = (bf16)v.w;
  *(bf16x4*)(dst + (size_t)seg * (D_ * D_) + local) = o;
}

// ---------------- RMSNorm (fp32 in, bf16 out) ----------------
__global__ __launch_bounds__(256) void rmsnorm_f32_kernel(const float* __restrict__ x,
                                                          const float* __restrict__ w,
                                                          const float* __restrict__ b,
                                                          bf16* __restrict__ out) {
  int row = blockIdx.x;
  int c = row & (C_ - 1);
  int t = threadIdx.x;
  float4 xv = *(const float4*)(x + (size_t)row * D_ + t * 4);
  float ss = xv.x * xv.x + xv.y * xv.y + xv.z * xv.z + xv.w * xv.w;
#pragma unroll
  for (int m = 1; m < 64; m <<= 1) ss += __shfl_xor(ss, m, 64);
  __shared__ float red[4];
  if ((t & 63) == 0) red[t >> 6] = ss;
  __syncthreads();
  float tot = red[0] + red[1] + red[2] + red[3];
  float inv = rsqrtf(tot * (1.0f / D_) + EPSF);
  float4 wv = *(const float4*)(w + (size_t)c * D_ + t * 4);
  float4 bv = *(const float4*)(b + (size_t)c * D_ + t * 4);
  bf16x4 ov;
  ov[0] = (bf16)(wv.x * (xv.x * inv) + bv.x);
  ov[1] = (bf16)(wv.y * (xv.y * inv) + bv.y);
  ov[2] = (bf16)(wv.z * (xv.z * inv) + bv.z);
  ov[3] = (bf16)(wv.w * (xv.w * inv) + bv.w);
  *(bf16x4*)(out + (size_t)row * D_ + t * 4) = ov;
}

// ---------------- RMSNorm (bf16 in, bf16 out) ----------------
__global__ __launch_bounds__(256) void rmsnorm_bf16_kernel(const bf16* __restrict__ x,
                                                           const float* __restrict__ w,
                                                           const float* __restrict__ b,
                                                           bf16* __restrict__ out) {
  int row = blockIdx.x;
  int c = row & (C_ - 1);
  int t = threadIdx.x;
  bf16x4 xv = *(const bf16x4*)(x + (size_t)row * D_ + t * 4);
  float f0 = (float)xv[0], f1 = (float)xv[1], f2 = (float)xv[2], f3 = (float)xv[3];
  float ss = f0 * f0 + f1 * f1 + f2 * f2 + f3 * f3;
#pragma unroll
  for (int m = 1; m < 64; m <<= 1) ss += __shfl_xor(ss, m, 64);
  __shared__ float red[4];
  if ((t & 63) == 0) red[t >> 6] = ss;
  __syncthreads();
  float tot = red[0] + red[1] + red[2] + red[3];
  float inv = rsqrtf(tot * (1.0f / D_) + EPSF);
  float4 wv = *(const float4*)(w + (size_t)c * D_ + t * 4);
  float4 bv = *(const float4*)(b + (size_t)c * D_ + t * 4);
  bf16x4 ov;
  ov[0] = (bf16)(wv.x * (f0 * inv) + bv.x);
  ov[1] = (bf16)(wv.y * (f1 * inv) + bv.y);
  ov[2] = (bf16)(wv.z * (f2 * inv) + bv.z);
  ov[3] = (bf16)(wv.w * (f3 * inv) + bv.w);
  *(bf16x4*)(out + (size_t)row * D_ + t * 4) = ov;
}

// ---------------- GEMM (m97 structure): C[m,n] = sum_k A[m,k] W[n,k] (+bias) (+R) ----------------
template <int BMt, int BNt>
__global__ __launch_bounds__(256) void gemm_lds(const bf16* __restrict__ A,
                                                const bf16* __restrict__ W,
                                                const float* __restrict__ bias,
                                                const bf16* __restrict__ R,
                                                bf16* __restrict__ Cout,
                                                int M, int N, int K) {
  constexpr int MT = BMt / 32;
  constexpr int NT = BNt / 32;
  __shared__ bf16 sa[BMt * BK];
  __shared__ bf16 sb[BNt * BK];
  int t = threadIdx.x, l = t & 63, w = t >> 6;
  int m0 = blockIdx.y * BMt;
  int n0 = blockIdx.x * BNt;
  int wm = (w >> 1) * (BMt / 2), wn = (w & 1) * (BNt / 2);
  int lm = l & 15, lq = l >> 4;
  f32x4 acc[MT][NT] = {};

  for (int k0 = 0; k0 < K; k0 += BK) {
    __syncthreads();
#pragma unroll
    for (int p = 0; p < BMt / 64; ++p) {
      int lin = p * 256 + t;
      async16(A + (size_t)(m0 + (lin >> 2)) * K + k0 + (lin & 3) * 8, sa + lin * 8);
    }
#pragma unroll
    for (int p = 0; p < BNt / 64; ++p) {
      int lin = p * 256 + t;
      async16(W + (size_t)(n0 + (lin >> 2)) * K + k0 + (lin & 3) * 8, sb + lin * 8);
    }
    __syncthreads();
    bf16x8 af[MT], bfr[NT];
#pragma unroll
    for (int mt = 0; mt < MT; ++mt)
      af[mt] = *(const bf16x8*)(sa + (wm + mt * 16 + lm) * BK + lq * 8);
#pragma unroll
    for (int nt = 0; nt < NT; ++nt)
      bfr[nt] = *(const bf16x8*)(sb + (wn + nt * 16 + lm) * BK + lq * 8);
#pragma unroll
    for (int mt = 0; mt < MT; ++mt)
#pragma unroll
      for (int nt = 0; nt < NT; ++nt)
        acc[mt][nt] = mfma16(af[mt], bfr[nt], acc[mt][nt]);
  }
#pragma unroll
  for (int mt = 0; mt < MT; ++mt)
#pragma unroll
    for (int nt = 0; nt < NT; ++nt) {
      int col = n0 + wn + nt * 16 + lm;
      float bb = bias ? bias[col] : 0.0f;
#pragma unroll
      for (int r = 0; r < 4; ++r) {
        int row = m0 + wm + mt * 16 + lq * 4 + r;
        float v = acc[mt][nt][r] + bb;
        if (R) v += (float)R[(size_t)row * N + col];
        Cout[(size_t)row * N + col] = (bf16)v;
      }
    }
}

// ---------------- Fused FFN tail: wx=A@Ww^T+bw, hv=A@Wv^T+bv (same block),
// out = x3 + (wx*sigmoid(beta*wx))*hv, fp32 out. Removes ffn_final + intermediates.
__global__ __launch_bounds__(256) void gemm_ffn_kernel(const bf16* __restrict__ A,
                                                       const bf16* __restrict__ Ww,
                                                       const bf16* __restrict__ Wv,
                                                       const float* __restrict__ bw,
                                                       const float* __restrict__ bv,
                                                       const bf16* __restrict__ x3,
                                                       const float* __restrict__ beta_p,
                                                       float* __restrict__ out) {
  __shared__ bf16 sa[64 * BK];
  __shared__ bf16 sb1[64 * BK];
  __shared__ bf16 sb2[64 * BK];
  int t = threadIdx.x, l = t & 63, w = t >> 6;
  int m0 = blockIdx.y * 64, n0 = blockIdx.x * 64;
  int wm = (w >> 1) * 32, wn = (w & 1) * 32;
  int lm = l & 15, lq = l >> 4;
  float beta = beta_p[0];
  f32x4 acc1[2][2] = {}, acc2[2][2] = {};

  for (int k0 = 0; k0 < D_; k0 += BK) {
    __syncthreads();
    async16(A + (size_t)(m0 + (t >> 2)) * D_ + k0 + (t & 3) * 8, sa + t * 8);
    async16(Ww + (size_t)(n0 + (t >> 2)) * D_ + k0 + (t & 3) * 8, sb1 + t * 8);
    async16(Wv + (size_t)(n0 + (t >> 2)) * D_ + k0 + (t & 3) * 8, sb2 + t * 8);
    __syncthreads();
    bf16x8 af[2], b1f[2], b2f[2];
#pragma unroll
    for (int mt = 0; mt < 2; ++mt)
      af[mt] = *(const bf16x8*)(sa + (wm + mt * 16 + lm) * BK + lq * 8);
#pragma unroll
    for (int nt = 0; nt < 2; ++nt) {
      b1f[nt] = *(const bf16x8*)(sb1 + (wn + nt * 16 + lm) * BK + lq * 8);
      b2f[nt] = *(const bf16x8*)(sb2 + (wn + nt * 16 + lm) * BK + lq * 8);
    }
#pragma unroll
    for (int mt = 0; mt < 2; ++mt)
#pragma unroll
      for (int nt = 0; nt < 2; ++nt) {
        acc1[mt][nt] = mfma16(af[mt], b1f[nt], acc1[mt][nt]);
        acc2[mt][nt] = mfma16(af[mt], b2f[nt], acc2[mt][nt]);
      }
  }
#pragma unroll
  for (int mt = 0; mt < 2; ++mt)
#pragma unroll
    for (int nt = 0; nt < 2; ++nt) {
      int col = n0 + wn + nt * 16 + lm;
      float bbw = bw[col], bbv = bv[col];
#pragma unroll
      for (int r = 0; r < 4; ++r) {
        int row = m0 + wm + mt * 16 + lq * 4 + r;
        float z = acc1[mt][nt][r] + bbw;
        float g = acc2[mt][nt][r] + bbv;
        float sw = z / (1.0f + __expf(-beta * z));
        out[(size_t)row * D_ + col] = (float)x3[(size_t)row * D_ + col] + sw * g;
      }
    }
}

// ---------------- prep: RoPE (q,k -> qr,kr head-major) + V transpose, fused ----------------
__global__ __launch_bounds__(256) void prep_kernel(const bf16* __restrict__ qkv,
                                                   bf16* __restrict__ qr,
                                                   bf16* __restrict__ kr,
                                                   bf16* __restrict__ vt) {
  __shared__ bf16 tile[64][65];
  int t = threadIdx.x;
  int blk = blockIdx.x;  // B*H*(C/64)
  int ct = blk & 15;
  int h = (blk >> 4) & 15;
  int b = blk >> 8;
  int c0 = ct * 64;
  size_t hb = (size_t)((b * H_ + h) * C_);

#pragma unroll
  for (int p = 0; p < 2; ++p) {
    int row = p * 32 + (t >> 3);
    int col = (t & 7) * 8;
    int c = c0 + row;
    size_t gq = (size_t)(b * C_ + c) * (3 * D_) + h * DH_ + col;
    bf16x8 qv = *(const bf16x8*)(qkv + gq);
    bf16x8 kv = *(const bf16x8*)(qkv + gq + D_);
    bf16x8 qo, ko;
#pragma unroll
    for (int j = 0; j < 4; ++j) {
      int i = (col >> 1) + j;  // pair index, theta = 10000^(-2(i-1)/64) per reference
      float theta = exp2f(-13.287712379549449f * (2.0f * ((float)i - 1.0f) / 64.0f));
      float ang = (float)c * theta;
      float sv = __sinf(ang), cv = __cosf(ang);
      float qe = (float)qv[2 * j], qo_ = (float)qv[2 * j + 1];
      float ke = (float)kv[2 * j], ko_ = (float)kv[2 * j + 1];
      qo[2 * j] = (bf16)(qe * cv + qo_ * sv);
      qo[2 * j + 1] = (bf16)(qo_ * cv - qe * sv);
      ko[2 * j] = (bf16)(ke * cv + ko_ * sv);
      ko[2 * j + 1] = (bf16)(ko_ * cv - ke * sv);
    }
    *(bf16x8*)(qr + (hb + c) * DH_ + col) = qo;
    *(bf16x8*)(kr + (hb + c) * DH_ + col) = ko;
  }

#pragma unroll
  for (int p = 0; p < 16; ++p) {
    int lin = p * 256 + t;
    int cl = lin >> 6, dh = lin & 63;
    tile[dh][cl] = qkv[(size_t)(b * C_ + c0 + cl) * (3 * D_) + 2 * D_ + h * DH_ + dh];
  }
  __syncthreads();
  size_t vbase = (size_t)((b * H_ + h) * DH_) * C_;
#pragma unroll
  for (int p = 0; p < 16; ++p) {
    int lin = p * 256 + t;
    int dh = lin >> 6, cl = lin & 63;
    vt[vbase + (size_t)dh * C_ + c0 + cl] = tile[dh][cl];
  }
}

// ---------------- Fused attention, j-split across 2 blocks; partial (yacc,den) out ----------------
// blk = b*512 + h*32 + it*2 + half; block covers i-rows [it*64, it*64+64), j in [half*512, half*512+512)
__global__ __launch_bounds__(256) void attn_kernel(const bf16* __restrict__ qkv,
                                                   const bf16* __restrict__ qr,
                                                   const bf16* __restrict__ kr,
                                                   const bf16* __restrict__ vt,
                                                   float* __restrict__ yp,
                                                   float* __restrict__ dp) {
  __shared__ bf16 sk[64 * 72];     // unrotated K tile [j][dh]
  __shared__ bf16 skr[64 * 72];    // rotated K tile  [j][dh]
  __shared__ bf16 sv[64 * 72];     // V^T tile        [dh][j]
  __shared__ bf16 pl[4][16 * 72];  // per-wave P tile [i][j]
  int t = threadIdx.x, l = t & 63, w = t >> 6;
  int blk = blockIdx.x;            // B*H*16*2 = 1024
  int half = blk & 1;
  int it = (blk >> 1) & 15;
  int h = (blk >> 5) & 15;
  int b = blk >> 9;
  int i_base = it * 64 + w * 16;
  int lm = l & 15, lq = l >> 4;
  const float scale = 0.125f;
  int jf = half << 9;  // 0 or 512

  size_t hq = (size_t)h * DH_;
  size_t qrow = (size_t)(b * C_ + i_base + lm) * (3 * D_) + hq;
  size_t hb = (size_t)((b * H_ + h) * C_);
  bf16x8 qp[2], qrf[2];
#pragma unroll
  for (int kk = 0; kk < 2; ++kk) {
    qp[kk] = *(const bf16x8*)(qkv + qrow + kk * 32 + lq * 8);
    qrf[kk] = *(const bf16x8*)(qr + (hb + i_base + lm) * DH_ + kk * 32 + lq * 8);
  }

  float den[4] = {0.f, 0.f, 0.f, 0.f};
  f32x4 yacc[4] = {};
  int i_max = i_base + 15;
  size_t kbase = (size_t)(b * C_) * (3 * D_) + D_ + hq;
  size_t krbase = hb * DH_;
  size_t vtbase = (size_t)((b * H_ + h) * DH_) * C_;
  int sr = t >> 3;       // 0..31
  int sc = (t & 7) * 8;  // 0..56

  // Prefetch registers: NAMED SCALARS ONLY (round 6: arrays/lambda -> scratch spill).
  int4 pk0, pk1, pkr0, pkr1, pv0, pv1;
#define FETCH_TILE(J0)                                                               \
  pk0 = *(const int4*)(qkv + kbase + (size_t)((J0) + sr) * (3 * D_) + sc);           \
  pk1 = *(const int4*)(qkv + kbase + (size_t)((J0) + 32 + sr) * (3 * D_) + sc);      \
  pkr0 = *(const int4*)(kr + krbase + (size_t)((J0) + sr) * DH_ + sc);               \
  pkr1 = *(const int4*)(kr + krbase + (size_t)((J0) + 32 + sr) * DH_ + sc);          \
  pv0 = *(const int4*)(vt + vtbase + (size_t)sr * C_ + (J0) + sc);                   \
  pv1 = *(const int4*)(vt + vtbase + (size_t)(32 + sr) * C_ + (J0) + sc);

  FETCH_TILE(jf)

  for (int j0 = jf; j0 < jf + 512; j0 += 64) {
    __syncthreads();
    *(int4*)(sk + sr * 72 + sc) = pk0;
    *(int4*)(sk + (32 + sr) * 72 + sc) = pk1;
    *(int4*)(skr + sr * 72 + sc) = pkr0;
    *(int4*)(skr + (32 + sr) * 72 + sc) = pkr1;
    *(int4*)(sv + sr * 72 + sc) = pv0;
    *(int4*)(sv + (32 + sr) * 72 + sc) = pv1;
    __syncthreads();
    if (j0 + 64 < jf + 512) {
      FETCH_TILE(j0 + 64)
    }
    // denominator: unrotated q.k over this j-half
#pragma unroll
    for (int js = 0; js < 64; js += 16) {
      bf16x8 kf0 = *(const bf16x8*)(sk + (js + lm) * 72 + lq * 8);
      bf16x8 kf1 = *(const bf16x8*)(sk + (js + lm) * 72 + 32 + lq * 8);
      f32x4 s = {0.f, 0.f, 0.f, 0.f};
      s = mfma16(qp[0], kf0, s);
      s = mfma16(qp[1], kf1, s);
#pragma unroll
      for (int r = 0; r < 4; ++r) den[r] += __expf(s[r] * scale);
    }
    // numerator + PV: causal tiles only (wave-uniform guard)
    if (j0 <= i_max) {
#pragma unroll
      for (int js = 0; js < 64; js += 16) {
        bf16x8 kf0 = *(const bf16x8*)(skr + (js + lm) * 72 + lq * 8);
        bf16x8 kf1 = *(const bf16x8*)(skr + (js + lm) * 72 + 32 + lq * 8);
        f32x4 s = {0.f, 0.f, 0.f, 0.f};
        s = mfma16(qrf[0], kf0, s);
        s = mfma16(qrf[1], kf1, s);
#pragma unroll
        for (int r = 0; r < 4; ++r) {
          int jg = j0 + js + lm;
          int ig = i_base + lq * 4 + r;
          float p = (jg <= ig) ? __expf(s[r] * scale) : 0.0f;
          pl[w][(lq * 4 + r) * 72 + js + lm] = (bf16)p;
        }
      }
      __builtin_amdgcn_wave_barrier();
      bf16x8 pf0 = *(const bf16x8*)(pl[w] + lm * 72 + lq * 8);
      bf16x8 pf1 = *(const bf16x8*)(pl[w] + lm * 72 + 32 + lq * 8);
#pragma unroll
      for (int tt = 0; tt < 4; ++tt) {
        bf16x8 vf0 = *(const bf16x8*)(sv + (tt * 16 + lm) * 72 + lq * 8);
        bf16x8 vf1 = *(const bf16x8*)(sv + (tt * 16 + lm) * 72 + 32 + lq * 8);
        yacc[tt] = mfma16(pf0, vf0, mfma16(pf1, vf1, yacc[tt]));
      }
      __builtin_amdgcn_wave_barrier();
    }
  }
#undef FETCH_TILE
  // partial den: reduce across lm lanes, lane lm==0 stores
#pragma unroll
  for (int r = 0; r < 4; ++r) {
    float d = den[r];
    d += __shfl_xor(d, 1, 64);
    d += __shfl_xor(d, 2, 64);
    d += __shfl_xor(d, 4, 64);
    d += __shfl_xor(d, 8, 64);
    if (lm == 0) dp[(size_t)blk * 64 + w * 16 + lq * 4 + r] = d;
  }
  // partial yacc (unnormalized)
  size_t yb = (size_t)blk * 4096;
#pragma unroll
  for (int tt = 0; tt < 4; ++tt)
#pragma unroll
    for (int r = 0; r < 4; ++r)
      yp[yb + (size_t)(w * 16 + lq * 4 + r) * 64 + tt * 16 + lm] = yacc[tt][r];
}

// ---------------- combine halves: y = (y0+y1)/(d0+d1), bf16 head-major -> row-major ----------------
__global__ __launch_bounds__(256) void combine_kernel(const float* __restrict__ yp,
                                                      const float* __restrict__ dp,
                                                      bf16* __restrict__ y) {
  int cb = blockIdx.x;  // ((b*H+h)*16 + it), 512 blocks
  int it = cb & 15;
  int h = (cb >> 4) & 15;
  int b = cb >> 8;
  int t = threadIdx.x;
  int row = t >> 2;            // 0..63
  int cg = (t & 3) * 16;       // col group start
  size_t p0 = (size_t)(cb * 2) * 4096 + (size_t)row * 64 + cg;
  size_t p1 = p0 + 4096;
  float inv = 1.0f / (dp[(size_t)(cb * 2) * 64 + row] + dp[(size_t)(cb * 2 + 1) * 64 + row]);
  bf16x8 o0, o1;
#pragma unroll
  for (int c = 0; c < 8; ++c) o0[c] = (bf16)((yp[p0 + c] + yp[p1 + c]) * inv);
#pragma unroll
  for (int c = 0; c < 8; ++c) o1[c] = (bf16)((yp[p0 + 8 + c] + yp[p1 + 8 + c]) * inv);
  size_t ob = (size_t)(b * C_ + it * 64 + row) * D_ + h * DH_ + cg;
  *(bf16x8*)(y + ob) = o0;
  *(bf16x8*)(y + ob + 8) = o1;
}

extern "C" void kernel_launch(void* const* d_in, const int* in_sizes, int n_in,
                              void* d_out, int out_size, void* d_ws, size_t ws_size,
                              hipStream_t stream) {
  const float* x = (const float*)d_in[0];
  const float* rms_w = (const float*)d_in[1];
  const float* rms_b = (const float*)d_in[2];
  const float* Wqkv = (const float*)d_in[3];
  const float* Wout = (const float*)d_in[4];
  const float* bout = (const float*)d_in[5];
  const float* Wf = (const float*)d_in[6];
  const float* bfp = (const float*)d_in[7];
  const float* Ww = (const float*)d_in[8];
  const float* bw = (const float*)d_in[9];
  const float* Wv = (const float*)d_in[10];
  const float* bv = (const float*)d_in[11];
  const float* beta = (const float*)d_in[12];
  float* out = (float*)d_out;

  // ws_size = 256 MB (observed via harness poison). Non-aliased layout, ~75 MB total.
  bf16* ws = (bf16*)d_ws;
  const size_t DD = (size_t)D_ * D_;  // 1,048,576
  const size_t MC = (size_t)B_ * C_;  // 2048
  bf16* wb = ws;                      // weights bf16: Wqkv(3DD), Wout, Wf, Ww, Wv  = 7DD
  bf16* x1 = ws + 7 * DD;
  bf16* qkv = ws + 9 * DD;            // 6DD
  bf16* qr = ws + 15 * DD;
  bf16* kr = ws + 17 * DD;
  bf16* vt = ws + 19 * DD;
  bf16* x2 = ws + 21 * DD;
  bf16* x3 = ws + 23 * DD;
  bf16* hbuf = ws + 25 * DD;
  float* yp = (float*)(ws + 28 * DD);         // 1024 * 4096 f32 = 16 MB
  float* dp = yp + (size_t)1024 * 4096;       // 64 K f32
  bf16* y = (bf16*)d_out;  // 4 MB bf16 inside 8 MB fp32 d_out; dead before final fp32 write

  cvt_all_kernel<<<7 * 1024, 256, 0, stream>>>(Wqkv, Wout, Wf, Ww, Wv, wb);
  rmsnorm_f32_kernel<<<MC, 256, 0, stream>>>(x, rms_w, rms_b, x1);
  gemm_lds<128, 64><<<dim3(3 * D_ / 64, MC / 128), 256, 0, stream>>>(
      x1, wb, nullptr, nullptr, qkv, MC, 3 * D_, D_);
  prep_kernel<<<B_ * H_ * (C_ / 64), 256, 0, stream>>>(qkv, qr, kr, vt);
  attn_kernel<<<B_ * H_ * 16 * 2, 256, 0, stream>>>(qkv, qr, kr, vt, yp, dp);
  combine_kernel<<<B_ * H_ * 16, 256, 0, stream>>>(yp, dp, y);
  gemm_lds<64, 64><<<dim3(D_ / 64, MC / 64), 256, 0, stream>>>(
      y, wb + 3 * DD, bout, x1, x2, MC, D_, D_);
  rmsnorm_bf16_kernel<<<MC, 256, 0, stream>>>(x2, rms_w, rms_b, x3);
  gemm_lds<64, 64><<<dim3(D_ / 64, MC / 64), 256, 0, stream>>>(
      x3, wb + 4 * DD, bfp, nullptr, hbuf, MC, D_, D_);
  gemm_ffn_kernel<<<dim3(D_ / 64, MC / 64), 256, 0, stream>>>(
      hbuf, wb + 5 * DD, wb + 6 * DD, bw, bv, x3, beta, out);
}